// Round 1
// baseline (1236.596 us; speedup 1.0000x reference)
//
#include <hip/hip_runtime.h>
#include <cmath>

#define N_NODES 50000
#define E_EDGES 800000
#define HID 128
#define HEADS 4
#define HD 32
#define EDIM 16
#define EGD 32
#define ROWS 8

__device__ __forceinline__ float gelu_f(float z) {
    return 0.5f * z * (1.0f + erff(z * 0.7071067811865476f));
}
__device__ __forceinline__ float sigmoid_f(float z) {
    return 1.0f / (1.0f + expf(-z));
}

// ---------------- K1: LN1 + QKV projection (8 rows / 128-thread block) ----------------
__global__ void __launch_bounds__(128) k1_ln_qkv(
    const float* __restrict__ x, const float* __restrict__ g1, const float* __restrict__ b1,
    const float* __restrict__ Wq, const float* __restrict__ Wk, const float* __restrict__ Wv,
    float* __restrict__ Q, float* __restrict__ K, float* __restrict__ V)
{
    __shared__ float xn[ROWS][HID];
    __shared__ float red[2][ROWS][2];
    const int l = threadIdx.x;
    const int wid = l >> 6, lane = l & 63;
    const int base = blockIdx.x * ROWS;
    float xv[ROWS];
    #pragma unroll
    for (int r = 0; r < ROWS; ++r) xv[r] = x[(size_t)(base + r) * HID + l];
    #pragma unroll
    for (int r = 0; r < ROWS; ++r) {
        float s1 = xv[r], s2 = xv[r] * xv[r];
        #pragma unroll
        for (int m = 1; m < 64; m <<= 1) { s1 += __shfl_xor(s1, m); s2 += __shfl_xor(s2, m); }
        if (lane == 0) { red[wid][r][0] = s1; red[wid][r][1] = s2; }
    }
    __syncthreads();
    const float gl = g1[l], bl = b1[l];
    #pragma unroll
    for (int r = 0; r < ROWS; ++r) {
        float s1 = red[0][r][0] + red[1][r][0];
        float s2 = red[0][r][1] + red[1][r][1];
        float mu = s1 * (1.0f / HID);
        float var = s2 * (1.0f / HID) - mu * mu;
        float rstd = rsqrtf(var + 1e-5f);
        xn[r][l] = (xv[r] - mu) * rstd * gl + bl;
    }
    __syncthreads();
    float aq[ROWS], ak[ROWS], av[ROWS];
    #pragma unroll
    for (int r = 0; r < ROWS; ++r) { aq[r] = 0.f; ak[r] = 0.f; av[r] = 0.f; }
    for (int k = 0; k < HID; ++k) {
        float wq = Wq[k * HID + l], wk = Wk[k * HID + l], wv = Wv[k * HID + l];
        #pragma unroll
        for (int r = 0; r < ROWS; ++r) {
            float xr = xn[r][k];
            aq[r] = fmaf(xr, wq, aq[r]);
            ak[r] = fmaf(xr, wk, ak[r]);
            av[r] = fmaf(xr, wv, av[r]);
        }
    }
    #pragma unroll
    for (int r = 0; r < ROWS; ++r) {
        Q[(size_t)(base + r) * HID + l] = aq[r];
        K[(size_t)(base + r) * HID + l] = ak[r];
        V[(size_t)(base + r) * HID + l] = av[r];
    }
}

// ---------------- K2a: per-edge QK^T dots (32 lanes / edge) ----------------
__global__ void __launch_bounds__(256) k2a_qkdot(
    const int* __restrict__ ei, const float* __restrict__ Q, const float* __restrict__ K,
    float* __restrict__ logits)
{
    const int tid = blockIdx.x * 256 + threadIdx.x;
    const int e = tid >> 5;
    const int s = threadIdx.x & 31;
    const int src = ei[e];
    const int dst = ei[E_EDGES + e];
    const float4* qp = (const float4*)(Q + (size_t)dst * HID);
    const float4* kp = (const float4*)(K + (size_t)src * HID);
    float4 q = qp[s], k = kp[s];
    float p = q.x * k.x + q.y * k.y + q.z * k.z + q.w * k.w;
    p += __shfl_xor(p, 1);
    p += __shfl_xor(p, 2);
    p += __shfl_xor(p, 4);
    // head h dot lives in lanes [8h, 8h+8) of each 32-lane half
    float hv = __shfl(p, (threadIdx.x & 32) + ((s & 3) << 3));
    if (s < 4) logits[(size_t)e * 4 + s] = hv * 0.17677669529663689f; // HD^-0.5
}

// ---------------- K2b: edge-attr bias MLP + atomicMax into m ----------------
__global__ void __launch_bounds__(256) k2b_bias_max(
    const int* __restrict__ ei, const float* __restrict__ ea,
    const float* __restrict__ Wea1, const float* __restrict__ bea1,
    const float* __restrict__ Wea2, const float* __restrict__ bea2,
    float* __restrict__ logits, float* __restrict__ mbuf)
{
    const int e = blockIdx.x * 256 + threadIdx.x;
    const float4* eap = (const float4*)(ea + (size_t)e * EDIM);
    float4 v0 = eap[0], v1 = eap[1], v2 = eap[2], v3 = eap[3];
    float a[EDIM] = {v0.x, v0.y, v0.z, v0.w, v1.x, v1.y, v1.z, v1.w,
                     v2.x, v2.y, v2.z, v2.w, v3.x, v3.y, v3.z, v3.w};
    float b0 = bea2[0], b1 = bea2[1], b2 = bea2[2], b3 = bea2[3];
    for (int j = 0; j < EGD; ++j) {
        float h = bea1[j];
        #pragma unroll
        for (int k = 0; k < EDIM; ++k) h = fmaf(a[k], Wea1[k * EGD + j], h);
        h = gelu_f(h);
        b0 = fmaf(h, Wea2[j * HEADS + 0], b0);
        b1 = fmaf(h, Wea2[j * HEADS + 1], b1);
        b2 = fmaf(h, Wea2[j * HEADS + 2], b2);
        b3 = fmaf(h, Wea2[j * HEADS + 3], b3);
    }
    float4 lg = *(const float4*)(logits + (size_t)e * 4);
    lg.x += b0; lg.y += b1; lg.z += b2; lg.w += b3;
    *(float4*)(logits + (size_t)e * 4) = lg;
    const int dst = ei[E_EDGES + e];
    int* mm = (int*)(mbuf + (size_t)dst * 4);
    // m initialized to 0 (== max(m,0) semantics); positive floats compare as ints
    if (lg.x > 0.f) atomicMax(mm + 0, __float_as_int(lg.x));
    if (lg.y > 0.f) atomicMax(mm + 1, __float_as_int(lg.y));
    if (lg.z > 0.f) atomicMax(mm + 2, __float_as_int(lg.z));
    if (lg.w > 0.f) atomicMax(mm + 3, __float_as_int(lg.w));
}

// ---------------- K3: el = exp(logit - m[dst]); s += el ----------------
__global__ void __launch_bounds__(256) k3_exp_sum(
    const int* __restrict__ ei, const float* __restrict__ mbuf,
    float* __restrict__ logits /* in: logits, out: el */, float* __restrict__ sbuf)
{
    const int e = blockIdx.x * 256 + threadIdx.x;
    const int dst = ei[E_EDGES + e];
    float4 lg = *(const float4*)(logits + (size_t)e * 4);
    const float4 mv = *(const float4*)(mbuf + (size_t)dst * 4);
    lg.x = expf(lg.x - mv.x);
    lg.y = expf(lg.y - mv.y);
    lg.z = expf(lg.z - mv.z);
    lg.w = expf(lg.w - mv.w);
    *(float4*)(logits + (size_t)e * 4) = lg;
    atomicAdd(sbuf + (size_t)dst * 4 + 0, lg.x);
    atomicAdd(sbuf + (size_t)dst * 4 + 1, lg.y);
    atomicAdd(sbuf + (size_t)dst * 4 + 2, lg.z);
    atomicAdd(sbuf + (size_t)dst * 4 + 3, lg.w);
}

// ---------------- K4: gate MLP + attn-weighted V scatter (1 wave / edge) ----------------
__global__ void __launch_bounds__(256) k4_gate_agg(
    const int* __restrict__ ei, const float* __restrict__ ea,
    const float* __restrict__ Weg1, const float* __restrict__ beg1,
    const float* __restrict__ Weg2, const float* __restrict__ beg2,
    const float* __restrict__ el, const float* __restrict__ sbuf,
    const float* __restrict__ V, float* __restrict__ agg)
{
    const int l = threadIdx.x & 63;
    const int e = blockIdx.x * 4 + (threadIdx.x >> 6);
    const int src = ei[e];
    const int dst = ei[E_EDGES + e];
    // each lane computes hidden unit (l & 31); both wave halves duplicate
    const int j = l & 31;
    const float4* eap = (const float4*)(ea + (size_t)e * EDIM);
    float4 v0 = eap[0], v1 = eap[1], v2 = eap[2], v3 = eap[3];
    float a[EDIM] = {v0.x, v0.y, v0.z, v0.w, v1.x, v1.y, v1.z, v1.w,
                     v2.x, v2.y, v2.z, v2.w, v3.x, v3.y, v3.z, v3.w};
    float h = beg1[j];
    #pragma unroll
    for (int k = 0; k < EDIM; ++k) h = fmaf(a[k], Weg1[k * EGD + j], h);
    h = gelu_f(h);
    // outputs d0 = l, d1 = l + 64
    float g0 = beg2[l], g1 = beg2[l + 64];
    for (int jj = 0; jj < EGD; ++jj) {
        float hj = __shfl(h, jj); // lane jj (<32) holds h1[jj]
        g0 = fmaf(hj, Weg2[jj * HID + l], g0);
        g1 = fmaf(hj, Weg2[jj * HID + l + 64], g1);
    }
    g0 = sigmoid_f(g0);
    g1 = sigmoid_f(g1);
    const int h0 = l >> 5;        // head of d0
    const int h1h = 2 + (l >> 5); // head of d1
    const float at0 = el[(size_t)e * 4 + h0] / (sbuf[(size_t)dst * 4 + h0] + 1e-10f);
    const float at1 = el[(size_t)e * 4 + h1h] / (sbuf[(size_t)dst * 4 + h1h] + 1e-10f);
    const float w0 = at0 * g0 * V[(size_t)src * HID + l];
    const float w1 = at1 * g1 * V[(size_t)src * HID + l + 64];
    atomicAdd(agg + (size_t)dst * HID + l, w0);
    atomicAdd(agg + (size_t)dst * HID + l + 64, w1);
}

// ---------------- K5: Wo + FiLM + residual + LN2 + FFN + residual ----------------
__global__ void __launch_bounds__(128) k5_out(
    const float* __restrict__ agg, const float* __restrict__ Wo, const float* __restrict__ bo,
    const float* __restrict__ gamma, const float* __restrict__ beta,
    const float* __restrict__ x,
    const float* __restrict__ g2, const float* __restrict__ b2,
    const float* __restrict__ Wf1, const float* __restrict__ bf1,
    const float* __restrict__ Wf2, const float* __restrict__ bf2,
    float* __restrict__ out)
{
    __shared__ float buf[ROWS][HID];
    __shared__ float hbuf[ROWS][2 * HID];
    __shared__ float red[2][ROWS][2];
    const int l = threadIdx.x;
    const int wid = l >> 6, lane = l & 63;
    const int base = blockIdx.x * ROWS;
    #pragma unroll
    for (int r = 0; r < ROWS; ++r) buf[r][l] = agg[(size_t)(base + r) * HID + l];
    __syncthreads();
    float acc[ROWS];
    #pragma unroll
    for (int r = 0; r < ROWS; ++r) acc[r] = 0.f;
    for (int k = 0; k < HID; ++k) {
        float w = Wo[k * HID + l];
        #pragma unroll
        for (int r = 0; r < ROWS; ++r) acc[r] = fmaf(buf[r][k], w, acc[r]);
    }
    float xl[ROWS];
    const float bol = bo[l];
    #pragma unroll
    for (int r = 0; r < ROWS; ++r) {
        float o = acc[r] + bol;
        size_t idx = (size_t)(base + r) * HID + l;
        o = fmaf(gamma[idx], o, beta[idx]);
        xl[r] = x[idx] + o;
    }
    __syncthreads(); // before reusing buf
    #pragma unroll
    for (int r = 0; r < ROWS; ++r) {
        float s1 = xl[r], s2 = xl[r] * xl[r];
        #pragma unroll
        for (int m = 1; m < 64; m <<= 1) { s1 += __shfl_xor(s1, m); s2 += __shfl_xor(s2, m); }
        if (lane == 0) { red[wid][r][0] = s1; red[wid][r][1] = s2; }
    }
    __syncthreads();
    const float g2l = g2[l], b2l = b2[l];
    #pragma unroll
    for (int r = 0; r < ROWS; ++r) {
        float s1 = red[0][r][0] + red[1][r][0];
        float s2 = red[0][r][1] + red[1][r][1];
        float mu = s1 * (1.0f / HID);
        float var = s2 * (1.0f / HID) - mu * mu;
        float rstd = rsqrtf(var + 1e-5f);
        buf[r][l] = (xl[r] - mu) * rstd * g2l + b2l;
    }
    __syncthreads();
    float f0[ROWS], f1[ROWS];
    #pragma unroll
    for (int r = 0; r < ROWS; ++r) { f0[r] = 0.f; f1[r] = 0.f; }
    for (int k = 0; k < HID; ++k) {
        float w0 = Wf1[k * 256 + l], w1 = Wf1[k * 256 + l + 128];
        #pragma unroll
        for (int r = 0; r < ROWS; ++r) {
            float xv = buf[r][k];
            f0[r] = fmaf(xv, w0, f0[r]);
            f1[r] = fmaf(xv, w1, f1[r]);
        }
    }
    const float bf1a = bf1[l], bf1b = bf1[l + 128];
    #pragma unroll
    for (int r = 0; r < ROWS; ++r) {
        hbuf[r][l] = gelu_f(f0[r] + bf1a);
        hbuf[r][l + 128] = gelu_f(f1[r] + bf1b);
    }
    __syncthreads();
    float o2[ROWS];
    #pragma unroll
    for (int r = 0; r < ROWS; ++r) o2[r] = 0.f;
    for (int k = 0; k < 2 * HID; ++k) {
        float w = Wf2[k * HID + l];
        #pragma unroll
        for (int r = 0; r < ROWS; ++r) o2[r] = fmaf(hbuf[r][k], w, o2[r]);
    }
    const float bf2l = bf2[l];
    #pragma unroll
    for (int r = 0; r < ROWS; ++r)
        out[(size_t)(base + r) * HID + l] = xl[r] + o2[r] + bf2l;
}

extern "C" void kernel_launch(void* const* d_in, const int* in_sizes, int n_in,
                              void* d_out, int out_size, void* d_ws, size_t ws_size,
                              hipStream_t stream) {
    const float* x     = (const float*)d_in[0];
    const int*   ei    = (const int*)d_in[1];
    const float* ea    = (const float*)d_in[2];
    const float* gamma = (const float*)d_in[3];
    const float* beta  = (const float*)d_in[4];
    const float* ln1_g = (const float*)d_in[5];
    const float* ln1_b = (const float*)d_in[6];
    const float* Wq    = (const float*)d_in[7];
    const float* Wk    = (const float*)d_in[8];
    const float* Wv    = (const float*)d_in[9];
    const float* Wo    = (const float*)d_in[10];
    const float* bo    = (const float*)d_in[11];
    const float* Wea1  = (const float*)d_in[12];
    const float* bea1  = (const float*)d_in[13];
    const float* Wea2  = (const float*)d_in[14];
    const float* bea2  = (const float*)d_in[15];
    const float* Weg1  = (const float*)d_in[16];
    const float* beg1  = (const float*)d_in[17];
    const float* Weg2  = (const float*)d_in[18];
    const float* beg2  = (const float*)d_in[19];
    const float* ln2_g = (const float*)d_in[20];
    const float* ln2_b = (const float*)d_in[21];
    const float* Wf1   = (const float*)d_in[22];
    const float* bf1   = (const float*)d_in[23];
    const float* Wf2   = (const float*)d_in[24];
    const float* bf2   = (const float*)d_in[25];

    float* ws = (float*)d_ws;
    float* Q      = ws;
    float* K      = Q + (size_t)N_NODES * HID;
    float* V      = K + (size_t)N_NODES * HID;
    float* logits = V + (size_t)N_NODES * HID;   // E*4 floats; becomes el in-place
    float* mbuf   = logits + (size_t)E_EDGES * 4;
    float* sbuf   = mbuf + (size_t)N_NODES * 4;
    float* agg    = sbuf + (size_t)N_NODES * 4;

    // zero m, s, agg (contiguous)
    hipMemsetAsync(mbuf, 0,
                   ((size_t)N_NODES * 4 * 2 + (size_t)N_NODES * HID) * sizeof(float),
                   stream);

    k1_ln_qkv<<<N_NODES / ROWS, 128, 0, stream>>>(x, ln1_g, ln1_b, Wq, Wk, Wv, Q, K, V);
    k2a_qkdot<<<E_EDGES / 8, 256, 0, stream>>>(ei, Q, K, logits);
    k2b_bias_max<<<E_EDGES / 256, 256, 0, stream>>>(ei, ea, Wea1, bea1, Wea2, bea2, logits, mbuf);
    k3_exp_sum<<<E_EDGES / 256, 256, 0, stream>>>(ei, mbuf, logits, sbuf);
    k4_gate_agg<<<E_EDGES / 4, 256, 0, stream>>>(ei, ea, Weg1, beg1, Weg2, beg2,
                                                 logits, sbuf, V, agg);
    k5_out<<<N_NODES / ROWS, 128, 0, stream>>>(agg, Wo, bo, gamma, beta, x,
                                               ln2_g, ln2_b, Wf1, bf1, Wf2, bf2,
                                               (float*)d_out);
}

// Round 2
// 1218.388 us; speedup vs baseline: 1.0149x; 1.0149x over previous
//
#include <hip/hip_runtime.h>
#include <cmath>

#define N_NODES 50000
#define E_EDGES 800000
#define HID 128
#define HEADS 4
#define HD 32
#define EDIM 16
#define EGD 32
#define ROWS 8
#define SCAN_BS 512
#define SCAN_NB ((N_NODES + SCAN_BS - 1) / SCAN_BS)

__device__ __forceinline__ float gelu_f(float z) {
    return 0.5f * z * (1.0f + erff(z * 0.7071067811865476f));
}
__device__ __forceinline__ float sigmoid_f(float z) {
    return 1.0f / (1.0f + expf(-z));
}

// ---------------- K1: LN1 + QKV projection (8 rows / 128-thread block) ----------------
__global__ void __launch_bounds__(128) k1_ln_qkv(
    const float* __restrict__ x, const float* __restrict__ g1, const float* __restrict__ b1,
    const float* __restrict__ Wq, const float* __restrict__ Wk, const float* __restrict__ Wv,
    float* __restrict__ Q, float* __restrict__ K, float* __restrict__ V)
{
    __shared__ float xn[ROWS][HID];
    __shared__ float red[2][ROWS][2];
    const int l = threadIdx.x;
    const int wid = l >> 6, lane = l & 63;
    const int base = blockIdx.x * ROWS;
    float xv[ROWS];
    #pragma unroll
    for (int r = 0; r < ROWS; ++r) xv[r] = x[(size_t)(base + r) * HID + l];
    #pragma unroll
    for (int r = 0; r < ROWS; ++r) {
        float s1 = xv[r], s2 = xv[r] * xv[r];
        #pragma unroll
        for (int m = 1; m < 64; m <<= 1) { s1 += __shfl_xor(s1, m); s2 += __shfl_xor(s2, m); }
        if (lane == 0) { red[wid][r][0] = s1; red[wid][r][1] = s2; }
    }
    __syncthreads();
    const float gl = g1[l], bl = b1[l];
    #pragma unroll
    for (int r = 0; r < ROWS; ++r) {
        float s1 = red[0][r][0] + red[1][r][0];
        float s2 = red[0][r][1] + red[1][r][1];
        float mu = s1 * (1.0f / HID);
        float var = s2 * (1.0f / HID) - mu * mu;
        float rstd = rsqrtf(var + 1e-5f);
        xn[r][l] = (xv[r] - mu) * rstd * gl + bl;
    }
    __syncthreads();
    float aq[ROWS], ak[ROWS], av[ROWS];
    #pragma unroll
    for (int r = 0; r < ROWS; ++r) { aq[r] = 0.f; ak[r] = 0.f; av[r] = 0.f; }
    for (int k = 0; k < HID; ++k) {
        float wq = Wq[k * HID + l], wk = Wk[k * HID + l], wv = Wv[k * HID + l];
        #pragma unroll
        for (int r = 0; r < ROWS; ++r) {
            float xr = xn[r][k];
            aq[r] = fmaf(xr, wq, aq[r]);
            ak[r] = fmaf(xr, wk, ak[r]);
            av[r] = fmaf(xr, wv, av[r]);
        }
    }
    #pragma unroll
    for (int r = 0; r < ROWS; ++r) {
        Q[(size_t)(base + r) * HID + l] = aq[r];
        K[(size_t)(base + r) * HID + l] = ak[r];
        V[(size_t)(base + r) * HID + l] = av[r];
    }
}

// ---------------- K2a: per-edge QK^T dots (32 lanes / edge) ----------------
__global__ void __launch_bounds__(256) k2a_qkdot(
    const int* __restrict__ ei, const float* __restrict__ Q, const float* __restrict__ K,
    float* __restrict__ logits)
{
    const int tid = blockIdx.x * 256 + threadIdx.x;
    const int e = tid >> 5;
    const int s = threadIdx.x & 31;
    const int src = ei[e];
    const int dst = ei[E_EDGES + e];
    const float4* qp = (const float4*)(Q + (size_t)dst * HID);
    const float4* kp = (const float4*)(K + (size_t)src * HID);
    float4 q = qp[s], k = kp[s];
    float p = q.x * k.x + q.y * k.y + q.z * k.z + q.w * k.w;
    p += __shfl_xor(p, 1);
    p += __shfl_xor(p, 2);
    p += __shfl_xor(p, 4);
    float hv = __shfl(p, (threadIdx.x & 32) + ((s & 3) << 3));
    if (s < 4) logits[(size_t)e * 4 + s] = hv * 0.17677669529663689f; // HD^-0.5
}

// ---------------- K2b: edge-attr bias MLP + atomicMax into m ----------------
__global__ void __launch_bounds__(256) k2b_bias_max(
    const int* __restrict__ ei, const float* __restrict__ ea,
    const float* __restrict__ Wea1, const float* __restrict__ bea1,
    const float* __restrict__ Wea2, const float* __restrict__ bea2,
    float* __restrict__ logits, float* __restrict__ mbuf)
{
    const int e = blockIdx.x * 256 + threadIdx.x;
    const float4* eap = (const float4*)(ea + (size_t)e * EDIM);
    float4 v0 = eap[0], v1 = eap[1], v2 = eap[2], v3 = eap[3];
    float a[EDIM] = {v0.x, v0.y, v0.z, v0.w, v1.x, v1.y, v1.z, v1.w,
                     v2.x, v2.y, v2.z, v2.w, v3.x, v3.y, v3.z, v3.w};
    float b0 = bea2[0], b1 = bea2[1], b2 = bea2[2], b3 = bea2[3];
    for (int j = 0; j < EGD; ++j) {
        float h = bea1[j];
        #pragma unroll
        for (int k = 0; k < EDIM; ++k) h = fmaf(a[k], Wea1[k * EGD + j], h);
        h = gelu_f(h);
        b0 = fmaf(h, Wea2[j * HEADS + 0], b0);
        b1 = fmaf(h, Wea2[j * HEADS + 1], b1);
        b2 = fmaf(h, Wea2[j * HEADS + 2], b2);
        b3 = fmaf(h, Wea2[j * HEADS + 3], b3);
    }
    float4 lg = *(const float4*)(logits + (size_t)e * 4);
    lg.x += b0; lg.y += b1; lg.z += b2; lg.w += b3;
    *(float4*)(logits + (size_t)e * 4) = lg;
    const int dst = ei[E_EDGES + e];
    int* mm = (int*)(mbuf + (size_t)dst * 4);
    if (lg.x > 0.f) atomicMax(mm + 0, __float_as_int(lg.x));
    if (lg.y > 0.f) atomicMax(mm + 1, __float_as_int(lg.y));
    if (lg.z > 0.f) atomicMax(mm + 2, __float_as_int(lg.z));
    if (lg.w > 0.f) atomicMax(mm + 3, __float_as_int(lg.w));
}

// ---------------- K3: el = exp(logit - m[dst]); s += el ----------------
__global__ void __launch_bounds__(256) k3_exp_sum(
    const int* __restrict__ ei, const float* __restrict__ mbuf,
    float* __restrict__ logits /* in: logits, out: el */, float* __restrict__ sbuf)
{
    const int e = blockIdx.x * 256 + threadIdx.x;
    const int dst = ei[E_EDGES + e];
    float4 lg = *(const float4*)(logits + (size_t)e * 4);
    const float4 mv = *(const float4*)(mbuf + (size_t)dst * 4);
    lg.x = expf(lg.x - mv.x);
    lg.y = expf(lg.y - mv.y);
    lg.z = expf(lg.z - mv.z);
    lg.w = expf(lg.w - mv.w);
    *(float4*)(logits + (size_t)e * 4) = lg;
    atomicAdd(sbuf + (size_t)dst * 4 + 0, lg.x);
    atomicAdd(sbuf + (size_t)dst * 4 + 1, lg.y);
    atomicAdd(sbuf + (size_t)dst * 4 + 2, lg.z);
    atomicAdd(sbuf + (size_t)dst * 4 + 3, lg.w);
}

// ---------------- CSR build ----------------
__global__ void __launch_bounds__(256) k0a_degree(
    const int* __restrict__ ei, int* __restrict__ deg)
{
    const int e = blockIdx.x * 256 + threadIdx.x;
    atomicAdd(deg + ei[E_EDGES + e], 1);
}

__global__ void __launch_bounds__(SCAN_BS) k0b_scan1(
    const int* __restrict__ deg, int* __restrict__ rowptr, int* __restrict__ bsum)
{
    __shared__ int sm[SCAN_BS];
    const int t = threadIdx.x;
    const int i = blockIdx.x * SCAN_BS + t;
    const int v = (i < N_NODES) ? deg[i] : 0;
    sm[t] = v;
    __syncthreads();
    #pragma unroll
    for (int off = 1; off < SCAN_BS; off <<= 1) {
        int add = (t >= off) ? sm[t - off] : 0;
        __syncthreads();
        sm[t] += add;
        __syncthreads();
    }
    if (i < N_NODES) rowptr[i] = sm[t] - v; // exclusive within block
    if (t == SCAN_BS - 1) bsum[blockIdx.x] = sm[t];
}

__global__ void k0c_scan2(int* __restrict__ bsum)
{
    if (threadIdx.x == 0 && blockIdx.x == 0) {
        int run = 0;
        for (int b = 0; b < SCAN_NB; ++b) { int t = bsum[b]; bsum[b] = run; run += t; }
    }
}

__global__ void __launch_bounds__(SCAN_BS) k0d_fixup(
    int* __restrict__ rowptr, int* __restrict__ wptr, const int* __restrict__ bsum)
{
    const int i = blockIdx.x * SCAN_BS + threadIdx.x;
    if (i < N_NODES) {
        int r = rowptr[i] + bsum[blockIdx.x];
        rowptr[i] = r;
        wptr[i] = r;
    }
    if (i == 0) rowptr[N_NODES] = E_EDGES;
}

__global__ void __launch_bounds__(256) k0e_scatter(
    const int* __restrict__ ei, int* __restrict__ wptr,
    int* __restrict__ eidx, int* __restrict__ esrc)
{
    const int e = blockIdx.x * 256 + threadIdx.x;
    const int d = ei[E_EDGES + e];
    const int pos = atomicAdd(wptr + d, 1);
    eidx[pos] = e;
    esrc[pos] = ei[e];
}

// ---------------- K4: CSR gather — one wave per dst node, no atomics ----------------
__global__ void __launch_bounds__(256) k4_gather(
    const int* __restrict__ rowptr, const int* __restrict__ eidx, const int* __restrict__ esrc,
    const float* __restrict__ ea,
    const float* __restrict__ Weg1, const float* __restrict__ beg1,
    const float* __restrict__ Weg2, const float* __restrict__ beg2,
    const float* __restrict__ el, const float* __restrict__ sbuf,
    const float* __restrict__ V, float* __restrict__ agg)
{
    const int l = threadIdx.x & 63;
    const int n = blockIdx.x * 4 + (threadIdx.x >> 6);
    if (n >= N_NODES) return;
    const int j = l & 31;
    // hoist weights to VGPRs (amortized over ~16 edges/node)
    float wa[EGD], wb[EGD], wg1[EDIM];
    #pragma unroll
    for (int jj = 0; jj < EGD; ++jj) {
        wa[jj] = Weg2[jj * HID + l];
        wb[jj] = Weg2[jj * HID + 64 + l];
    }
    #pragma unroll
    for (int k = 0; k < EDIM; ++k) wg1[k] = Weg1[k * EGD + j];
    const float bg1 = beg1[j];
    const float b20 = beg2[l], b21 = beg2[l + 64];
    const int h0 = l >> 5, h1 = 2 + (l >> 5);
    const float inv0 = 1.0f / (sbuf[(size_t)n * 4 + h0] + 1e-10f);
    const float inv1 = 1.0f / (sbuf[(size_t)n * 4 + h1] + 1e-10f);
    float acc0 = 0.f, acc1 = 0.f;
    const int pstart = rowptr[n], pend = rowptr[n + 1];
    for (int p = pstart; p < pend; ++p) {
        const int e = eidx[p];
        const int src = esrc[p];
        const float4* eap = (const float4*)(ea + (size_t)e * EDIM);
        float4 v0 = eap[0], v1 = eap[1], v2 = eap[2], v3 = eap[3];
        float h = bg1;
        h = fmaf(v0.x, wg1[0], h);  h = fmaf(v0.y, wg1[1], h);
        h = fmaf(v0.z, wg1[2], h);  h = fmaf(v0.w, wg1[3], h);
        h = fmaf(v1.x, wg1[4], h);  h = fmaf(v1.y, wg1[5], h);
        h = fmaf(v1.z, wg1[6], h);  h = fmaf(v1.w, wg1[7], h);
        h = fmaf(v2.x, wg1[8], h);  h = fmaf(v2.y, wg1[9], h);
        h = fmaf(v2.z, wg1[10], h); h = fmaf(v2.w, wg1[11], h);
        h = fmaf(v3.x, wg1[12], h); h = fmaf(v3.y, wg1[13], h);
        h = fmaf(v3.z, wg1[14], h); h = fmaf(v3.w, wg1[15], h);
        h = gelu_f(h);
        float g0 = b20, g1 = b21;
        #pragma unroll
        for (int jj = 0; jj < EGD; ++jj) {
            float hj = __shfl(h, jj);
            g0 = fmaf(hj, wa[jj], g0);
            g1 = fmaf(hj, wb[jj], g1);
        }
        g0 = sigmoid_f(g0);
        g1 = sigmoid_f(g1);
        const float at0 = el[(size_t)e * 4 + h0] * inv0;
        const float at1 = el[(size_t)e * 4 + h1] * inv1;
        acc0 = fmaf(at0 * g0, V[(size_t)src * HID + l], acc0);
        acc1 = fmaf(at1 * g1, V[(size_t)src * HID + l + 64], acc1);
    }
    agg[(size_t)n * HID + l] = acc0;
    agg[(size_t)n * HID + l + 64] = acc1;
}

// ---------------- K5: Wo + FiLM + residual + LN2 + FFN + residual ----------------
__global__ void __launch_bounds__(128) k5_out(
    const float* __restrict__ agg, const float* __restrict__ Wo, const float* __restrict__ bo,
    const float* __restrict__ gamma, const float* __restrict__ beta,
    const float* __restrict__ x,
    const float* __restrict__ g2, const float* __restrict__ b2,
    const float* __restrict__ Wf1, const float* __restrict__ bf1,
    const float* __restrict__ Wf2, const float* __restrict__ bf2,
    float* __restrict__ out)
{
    __shared__ float buf[ROWS][HID];
    __shared__ float hbuf[ROWS][2 * HID];
    __shared__ float red[2][ROWS][2];
    const int l = threadIdx.x;
    const int wid = l >> 6, lane = l & 63;
    const int base = blockIdx.x * ROWS;
    #pragma unroll
    for (int r = 0; r < ROWS; ++r) buf[r][l] = agg[(size_t)(base + r) * HID + l];
    __syncthreads();
    float acc[ROWS];
    #pragma unroll
    for (int r = 0; r < ROWS; ++r) acc[r] = 0.f;
    for (int k = 0; k < HID; ++k) {
        float w = Wo[k * HID + l];
        #pragma unroll
        for (int r = 0; r < ROWS; ++r) acc[r] = fmaf(buf[r][k], w, acc[r]);
    }
    float xl[ROWS];
    const float bol = bo[l];
    #pragma unroll
    for (int r = 0; r < ROWS; ++r) {
        float o = acc[r] + bol;
        size_t idx = (size_t)(base + r) * HID + l;
        o = fmaf(gamma[idx], o, beta[idx]);
        xl[r] = x[idx] + o;
    }
    __syncthreads();
    #pragma unroll
    for (int r = 0; r < ROWS; ++r) {
        float s1 = xl[r], s2 = xl[r] * xl[r];
        #pragma unroll
        for (int m = 1; m < 64; m <<= 1) { s1 += __shfl_xor(s1, m); s2 += __shfl_xor(s2, m); }
        if (lane == 0) { red[wid][r][0] = s1; red[wid][r][1] = s2; }
    }
    __syncthreads();
    const float g2l = g2[l], b2l = b2[l];
    #pragma unroll
    for (int r = 0; r < ROWS; ++r) {
        float s1 = red[0][r][0] + red[1][r][0];
        float s2 = red[0][r][1] + red[1][r][1];
        float mu = s1 * (1.0f / HID);
        float var = s2 * (1.0f / HID) - mu * mu;
        float rstd = rsqrtf(var + 1e-5f);
        buf[r][l] = (xl[r] - mu) * rstd * g2l + b2l;
    }
    __syncthreads();
    float f0[ROWS], f1[ROWS];
    #pragma unroll
    for (int r = 0; r < ROWS; ++r) { f0[r] = 0.f; f1[r] = 0.f; }
    for (int k = 0; k < HID; ++k) {
        float w0 = Wf1[k * 256 + l], w1 = Wf1[k * 256 + l + 128];
        #pragma unroll
        for (int r = 0; r < ROWS; ++r) {
            float xv = buf[r][k];
            f0[r] = fmaf(xv, w0, f0[r]);
            f1[r] = fmaf(xv, w1, f1[r]);
        }
    }
    const float bf1a = bf1[l], bf1b = bf1[l + 128];
    #pragma unroll
    for (int r = 0; r < ROWS; ++r) {
        hbuf[r][l] = gelu_f(f0[r] + bf1a);
        hbuf[r][l + 128] = gelu_f(f1[r] + bf1b);
    }
    __syncthreads();
    float o2[ROWS];
    #pragma unroll
    for (int r = 0; r < ROWS; ++r) o2[r] = 0.f;
    for (int k = 0; k < 2 * HID; ++k) {
        float w = Wf2[k * HID + l];
        #pragma unroll
        for (int r = 0; r < ROWS; ++r) o2[r] = fmaf(hbuf[r][k], w, o2[r]);
    }
    const float bf2l = bf2[l];
    #pragma unroll
    for (int r = 0; r < ROWS; ++r)
        out[(size_t)(base + r) * HID + l] = xl[r] + o2[r] + bf2l;
}

extern "C" void kernel_launch(void* const* d_in, const int* in_sizes, int n_in,
                              void* d_out, int out_size, void* d_ws, size_t ws_size,
                              hipStream_t stream) {
    const float* x     = (const float*)d_in[0];
    const int*   ei    = (const int*)d_in[1];
    const float* ea    = (const float*)d_in[2];
    const float* gamma = (const float*)d_in[3];
    const float* beta  = (const float*)d_in[4];
    const float* ln1_g = (const float*)d_in[5];
    const float* ln1_b = (const float*)d_in[6];
    const float* Wq    = (const float*)d_in[7];
    const float* Wk    = (const float*)d_in[8];
    const float* Wv    = (const float*)d_in[9];
    const float* Wo    = (const float*)d_in[10];
    const float* bo    = (const float*)d_in[11];
    const float* Wea1  = (const float*)d_in[12];
    const float* bea1  = (const float*)d_in[13];
    const float* Wea2  = (const float*)d_in[14];
    const float* bea2  = (const float*)d_in[15];
    const float* Weg1  = (const float*)d_in[16];
    const float* beg1  = (const float*)d_in[17];
    const float* Weg2  = (const float*)d_in[18];
    const float* beg2  = (const float*)d_in[19];
    const float* ln2_g = (const float*)d_in[20];
    const float* ln2_b = (const float*)d_in[21];
    const float* Wf1   = (const float*)d_in[22];
    const float* bf1   = (const float*)d_in[23];
    const float* Wf2   = (const float*)d_in[24];
    const float* bf2   = (const float*)d_in[25];

    float* ws = (float*)d_ws;
    float* Q      = ws;
    float* K      = Q + (size_t)N_NODES * HID;
    float* V      = K + (size_t)N_NODES * HID;
    float* logits = V + (size_t)N_NODES * HID;     // E*4 floats; becomes el in-place
    float* mbuf   = logits + (size_t)E_EDGES * 4;
    float* sbuf   = mbuf + (size_t)N_NODES * 4;
    int*   deg    = (int*)(sbuf + (size_t)N_NODES * 4);
    float* agg    = (float*)(deg + N_NODES);
    int*   rowptr = (int*)(agg + (size_t)N_NODES * HID);
    int*   wptr   = rowptr + (N_NODES + 1);
    int*   bsum   = wptr + N_NODES;
    int*   eidx   = bsum + SCAN_NB;
    int*   esrc   = eidx + E_EDGES;

    // zero mbuf, sbuf, deg (contiguous)
    hipMemsetAsync(mbuf, 0,
                   ((size_t)N_NODES * 4 * 2) * sizeof(float) + (size_t)N_NODES * sizeof(int),
                   stream);

    // CSR build (independent of K1/K2 chain)
    k0a_degree<<<E_EDGES / 256, 256, 0, stream>>>(ei, deg);
    k0b_scan1<<<SCAN_NB, SCAN_BS, 0, stream>>>(deg, rowptr, bsum);
    k0c_scan2<<<1, 64, 0, stream>>>(bsum);
    k0d_fixup<<<SCAN_NB, SCAN_BS, 0, stream>>>(rowptr, wptr, bsum);
    k0e_scatter<<<E_EDGES / 256, 256, 0, stream>>>(ei, wptr, eidx, esrc);

    k1_ln_qkv<<<N_NODES / ROWS, 128, 0, stream>>>(x, ln1_g, ln1_b, Wq, Wk, Wv, Q, K, V);
    k2a_qkdot<<<E_EDGES / 8, 256, 0, stream>>>(ei, Q, K, logits);
    k2b_bias_max<<<E_EDGES / 256, 256, 0, stream>>>(ei, ea, Wea1, bea1, Wea2, bea2, logits, mbuf);
    k3_exp_sum<<<E_EDGES / 256, 256, 0, stream>>>(ei, mbuf, logits, sbuf);
    k4_gather<<<(N_NODES + 3) / 4, 256, 0, stream>>>(rowptr, eidx, esrc, ea,
                                                     Weg1, beg1, Weg2, beg2,
                                                     logits, sbuf, V, agg);
    k5_out<<<N_NODES / ROWS, 128, 0, stream>>>(agg, Wo, bo, gamma, beta, x,
                                               ln2_g, ln2_b, Wf1, bf1, Wf2, bf2,
                                               (float*)d_out);
}

// Round 3
// 960.912 us; speedup vs baseline: 1.2869x; 1.2679x over previous
//
#include <hip/hip_runtime.h>
#include <cmath>

#define N_NODES 50000
#define E_EDGES 800000
#define HID 128
#define HEADS 4
#define HD 32
#define EDIM 16
#define EGD 32
#define ROWS 8
#define EB 64
#define SCAN_BS 512
#define SCAN_NB ((N_NODES + SCAN_BS - 1) / SCAN_BS)

__device__ __forceinline__ float gelu_f(float z) {
    return 0.5f * z * (1.0f + erff(z * 0.7071067811865476f));
}
__device__ __forceinline__ float sigmoid_f(float z) {
    return 1.0f / (1.0f + expf(-z));
}

// ---------------- K1: LN1 + QKV projection (8 rows / 128-thread block) ----------------
__global__ void __launch_bounds__(128) k1_ln_qkv(
    const float* __restrict__ x, const float* __restrict__ g1, const float* __restrict__ b1,
    const float* __restrict__ Wq, const float* __restrict__ Wk, const float* __restrict__ Wv,
    float* __restrict__ Q, float* __restrict__ K, float* __restrict__ V)
{
    __shared__ float xn[ROWS][HID];
    __shared__ float red[2][ROWS][2];
    const int l = threadIdx.x;
    const int wid = l >> 6, lane = l & 63;
    const int base = blockIdx.x * ROWS;
    float xv[ROWS];
    #pragma unroll
    for (int r = 0; r < ROWS; ++r) xv[r] = x[(size_t)(base + r) * HID + l];
    #pragma unroll
    for (int r = 0; r < ROWS; ++r) {
        float s1 = xv[r], s2 = xv[r] * xv[r];
        #pragma unroll
        for (int m = 1; m < 64; m <<= 1) { s1 += __shfl_xor(s1, m); s2 += __shfl_xor(s2, m); }
        if (lane == 0) { red[wid][r][0] = s1; red[wid][r][1] = s2; }
    }
    __syncthreads();
    const float gl = g1[l], bl = b1[l];
    #pragma unroll
    for (int r = 0; r < ROWS; ++r) {
        float s1 = red[0][r][0] + red[1][r][0];
        float s2 = red[0][r][1] + red[1][r][1];
        float mu = s1 * (1.0f / HID);
        float var = s2 * (1.0f / HID) - mu * mu;
        float rstd = rsqrtf(var + 1e-5f);
        xn[r][l] = (xv[r] - mu) * rstd * gl + bl;
    }
    __syncthreads();
    float aq[ROWS], ak[ROWS], av[ROWS];
    #pragma unroll
    for (int r = 0; r < ROWS; ++r) { aq[r] = 0.f; ak[r] = 0.f; av[r] = 0.f; }
    for (int k = 0; k < HID; ++k) {
        float wq = Wq[k * HID + l], wk = Wk[k * HID + l], wv = Wv[k * HID + l];
        #pragma unroll
        for (int r = 0; r < ROWS; ++r) {
            float xr = xn[r][k];
            aq[r] = fmaf(xr, wq, aq[r]);
            ak[r] = fmaf(xr, wk, ak[r]);
            av[r] = fmaf(xr, wv, av[r]);
        }
    }
    #pragma unroll
    for (int r = 0; r < ROWS; ++r) {
        Q[(size_t)(base + r) * HID + l] = aq[r];
        K[(size_t)(base + r) * HID + l] = ak[r];
        V[(size_t)(base + r) * HID + l] = av[r];
    }
}

// ---------------- K2a: per-edge QK^T dots (32 lanes / edge) ----------------
__global__ void __launch_bounds__(256) k2a_qkdot(
    const int* __restrict__ ei, const float* __restrict__ Q, const float* __restrict__ K,
    float* __restrict__ logits)
{
    const int tid = blockIdx.x * 256 + threadIdx.x;
    const int e = tid >> 5;
    const int s = threadIdx.x & 31;
    const int src = ei[e];
    const int dst = ei[E_EDGES + e];
    const float4* qp = (const float4*)(Q + (size_t)dst * HID);
    const float4* kp = (const float4*)(K + (size_t)src * HID);
    float4 q = qp[s], k = kp[s];
    float p = q.x * k.x + q.y * k.y + q.z * k.z + q.w * k.w;
    p += __shfl_xor(p, 1);
    p += __shfl_xor(p, 2);
    p += __shfl_xor(p, 4);
    float hv = __shfl(p, (threadIdx.x & 32) + ((s & 3) << 3));
    if (s < 4) logits[(size_t)e * 4 + s] = hv * 0.17677669529663689f; // HD^-0.5
}

// ---------------- K2b: edge-attr bias MLP + atomicMax into m ----------------
__global__ void __launch_bounds__(256) k2b_bias_max(
    const int* __restrict__ ei, const float* __restrict__ ea,
    const float* __restrict__ Wea1, const float* __restrict__ bea1,
    const float* __restrict__ Wea2, const float* __restrict__ bea2,
    float* __restrict__ logits, float* __restrict__ mbuf)
{
    const int e = blockIdx.x * 256 + threadIdx.x;
    const float4* eap = (const float4*)(ea + (size_t)e * EDIM);
    float4 v0 = eap[0], v1 = eap[1], v2 = eap[2], v3 = eap[3];
    float a[EDIM] = {v0.x, v0.y, v0.z, v0.w, v1.x, v1.y, v1.z, v1.w,
                     v2.x, v2.y, v2.z, v2.w, v3.x, v3.y, v3.z, v3.w};
    float b0 = bea2[0], b1 = bea2[1], b2 = bea2[2], b3 = bea2[3];
    for (int j = 0; j < EGD; ++j) {
        float h = bea1[j];
        #pragma unroll
        for (int k = 0; k < EDIM; ++k) h = fmaf(a[k], Wea1[k * EGD + j], h);
        h = gelu_f(h);
        b0 = fmaf(h, Wea2[j * HEADS + 0], b0);
        b1 = fmaf(h, Wea2[j * HEADS + 1], b1);
        b2 = fmaf(h, Wea2[j * HEADS + 2], b2);
        b3 = fmaf(h, Wea2[j * HEADS + 3], b3);
    }
    float4 lg = *(const float4*)(logits + (size_t)e * 4);
    lg.x += b0; lg.y += b1; lg.z += b2; lg.w += b3;
    *(float4*)(logits + (size_t)e * 4) = lg;
    const int dst = ei[E_EDGES + e];
    int* mm = (int*)(mbuf + (size_t)dst * 4);
    if (lg.x > 0.f) atomicMax(mm + 0, __float_as_int(lg.x));
    if (lg.y > 0.f) atomicMax(mm + 1, __float_as_int(lg.y));
    if (lg.z > 0.f) atomicMax(mm + 2, __float_as_int(lg.z));
    if (lg.w > 0.f) atomicMax(mm + 3, __float_as_int(lg.w));
}

// ---------------- K3: el = exp(logit - m[dst]); s += el ----------------
__global__ void __launch_bounds__(256) k3_exp_sum(
    const int* __restrict__ ei, const float* __restrict__ mbuf,
    float* __restrict__ logits /* in: logits, out: el */, float* __restrict__ sbuf)
{
    const int e = blockIdx.x * 256 + threadIdx.x;
    const int dst = ei[E_EDGES + e];
    float4 lg = *(const float4*)(logits + (size_t)e * 4);
    const float4 mv = *(const float4*)(mbuf + (size_t)dst * 4);
    lg.x = expf(lg.x - mv.x);
    lg.y = expf(lg.y - mv.y);
    lg.z = expf(lg.z - mv.z);
    lg.w = expf(lg.w - mv.w);
    *(float4*)(logits + (size_t)e * 4) = lg;
    atomicAdd(sbuf + (size_t)dst * 4 + 0, lg.x);
    atomicAdd(sbuf + (size_t)dst * 4 + 1, lg.y);
    atomicAdd(sbuf + (size_t)dst * 4 + 2, lg.z);
    atomicAdd(sbuf + (size_t)dst * 4 + 3, lg.w);
}

// ---------------- CSR build ----------------
__global__ void __launch_bounds__(256) k0a_degree(
    const int* __restrict__ ei, int* __restrict__ deg)
{
    const int e = blockIdx.x * 256 + threadIdx.x;
    atomicAdd(deg + ei[E_EDGES + e], 1);
}

__global__ void __launch_bounds__(SCAN_BS) k0b_scan1(
    const int* __restrict__ deg, int* __restrict__ rowptr, int* __restrict__ bsum)
{
    __shared__ int sm[SCAN_BS];
    const int t = threadIdx.x;
    const int i = blockIdx.x * SCAN_BS + t;
    const int v = (i < N_NODES) ? deg[i] : 0;
    sm[t] = v;
    __syncthreads();
    #pragma unroll
    for (int off = 1; off < SCAN_BS; off <<= 1) {
        int add = (t >= off) ? sm[t - off] : 0;
        __syncthreads();
        sm[t] += add;
        __syncthreads();
    }
    if (i < N_NODES) rowptr[i] = sm[t] - v;
    if (t == SCAN_BS - 1) bsum[blockIdx.x] = sm[t];
}

__global__ void k0c_scan2(int* __restrict__ bsum)
{
    if (threadIdx.x == 0 && blockIdx.x == 0) {
        int run = 0;
        for (int b = 0; b < SCAN_NB; ++b) { int t = bsum[b]; bsum[b] = run; run += t; }
    }
}

__global__ void __launch_bounds__(SCAN_BS) k0d_fixup(
    int* __restrict__ rowptr, int* __restrict__ wptr, const int* __restrict__ bsum)
{
    const int i = blockIdx.x * SCAN_BS + threadIdx.x;
    if (i < N_NODES) {
        int r = rowptr[i] + bsum[blockIdx.x];
        rowptr[i] = r;
        wptr[i] = r;
    }
    if (i == 0) rowptr[N_NODES] = E_EDGES;
}

__global__ void __launch_bounds__(256) k0e_scatter(
    const int* __restrict__ ei, int* __restrict__ wptr,
    int* __restrict__ eidx, int* __restrict__ esrc, int* __restrict__ pdst)
{
    const int e = blockIdx.x * 256 + threadIdx.x;
    const int d = ei[E_EDGES + e];
    const int pos = atomicAdd(wptr + d, 1);
    eidx[pos] = e;
    esrc[pos] = ei[e];
    pdst[pos] = d;
}

// ---------------- K4a: gate MLP (LDS-staged) + attn-V fold + run-length flush ----------------
__global__ void __launch_bounds__(256) k4a_gate_flush(
    const int* __restrict__ eidx, const int* __restrict__ esrc, const int* __restrict__ pdst,
    const float* __restrict__ ea,
    const float* __restrict__ Weg1, const float* __restrict__ beg1,
    const float* __restrict__ Weg2, const float* __restrict__ beg2,
    const float* __restrict__ el, const float* __restrict__ sbuf,
    const float* __restrict__ V, float* __restrict__ agg)
{
    __shared__ float hsm[EB][EGD];        // 64 edges x 32 hidden = 8 KB
    __shared__ float w1sm[EDIM * EGD];    // 2 KB
    const int t = threadIdx.x;
    const int p0 = blockIdx.x * EB;

    // stage Weg1
    w1sm[t] = Weg1[t];
    w1sm[t + 256] = Weg1[t + 256];
    __syncthreads();

    // ---- phase 1: layer-1, thread = (edge slot, 8 hidden units), each gelu once ----
    {
        const int s = t & 63;
        const int jg = t >> 6; // 0..3
        const int e = eidx[p0 + s];
        const float4* eap = (const float4*)(ea + (size_t)e * EDIM);
        float4 v0 = eap[0], v1 = eap[1], v2 = eap[2], v3 = eap[3];
        float a[EDIM] = {v0.x, v0.y, v0.z, v0.w, v1.x, v1.y, v1.z, v1.w,
                         v2.x, v2.y, v2.z, v2.w, v3.x, v3.y, v3.z, v3.w};
        #pragma unroll
        for (int jo = 0; jo < 8; ++jo) {
            const int j = jg * 8 + jo;
            float h = beg1[j];
            #pragma unroll
            for (int k = 0; k < EDIM; ++k) h = fmaf(a[k], w1sm[k * EGD + j], h);
            hsm[s][j] = gelu_f(h);
        }
    }
    __syncthreads();

    // ---- phase 2: layer-2 (pure FMA, h broadcast from LDS) + attn fold + flush ----
    const int w = t >> 6, l = t & 63;
    float wa[EGD], wb[EGD];
    #pragma unroll
    for (int jj = 0; jj < EGD; ++jj) {
        wa[jj] = Weg2[jj * HID + l];
        wb[jj] = Weg2[jj * HID + 64 + l];
    }
    const float b20 = beg2[l], b21 = beg2[l + 64];
    const int h0 = l >> 5, h1 = 2 + (l >> 5);
    const int sbase = w << 4; // this wave's 16 edge slots
    int cur = pdst[p0 + sbase];
    float inv0 = 1.0f / (sbuf[(size_t)cur * 4 + h0] + 1e-10f);
    float inv1 = 1.0f / (sbuf[(size_t)cur * 4 + h1] + 1e-10f);
    float acc0 = 0.f, acc1 = 0.f;
    for (int s = sbase; s < sbase + 16; ++s) {
        const int p = p0 + s;
        const int e = eidx[p];
        const int src = esrc[p];
        const int d = pdst[p];
        if (d != cur) { // wave-uniform branch
            atomicAdd(agg + (size_t)cur * HID + l, acc0);
            atomicAdd(agg + (size_t)cur * HID + 64 + l, acc1);
            acc0 = 0.f; acc1 = 0.f;
            cur = d;
            inv0 = 1.0f / (sbuf[(size_t)cur * 4 + h0] + 1e-10f);
            inv1 = 1.0f / (sbuf[(size_t)cur * 4 + h1] + 1e-10f);
        }
        float g0 = b20, g1 = b21;
        #pragma unroll
        for (int jj = 0; jj < EGD; jj += 4) {
            const float4 h4 = *(const float4*)&hsm[s][jj]; // same addr all lanes: broadcast
            g0 = fmaf(h4.x, wa[jj + 0], g0); g1 = fmaf(h4.x, wb[jj + 0], g1);
            g0 = fmaf(h4.y, wa[jj + 1], g0); g1 = fmaf(h4.y, wb[jj + 1], g1);
            g0 = fmaf(h4.z, wa[jj + 2], g0); g1 = fmaf(h4.z, wb[jj + 2], g1);
            g0 = fmaf(h4.w, wa[jj + 3], g0); g1 = fmaf(h4.w, wb[jj + 3], g1);
        }
        g0 = sigmoid_f(g0);
        g1 = sigmoid_f(g1);
        const float at0 = el[(size_t)e * 4 + h0] * inv0;
        const float at1 = el[(size_t)e * 4 + h1] * inv1;
        acc0 = fmaf(at0 * g0, V[(size_t)src * HID + l], acc0);
        acc1 = fmaf(at1 * g1, V[(size_t)src * HID + 64 + l], acc1);
    }
    atomicAdd(agg + (size_t)cur * HID + l, acc0);
    atomicAdd(agg + (size_t)cur * HID + 64 + l, acc1);
}

// ---------------- K5: Wo + FiLM + residual + LN2 + FFN + residual ----------------
__global__ void __launch_bounds__(128) k5_out(
    const float* __restrict__ agg, const float* __restrict__ Wo, const float* __restrict__ bo,
    const float* __restrict__ gamma, const float* __restrict__ beta,
    const float* __restrict__ x,
    const float* __restrict__ g2, const float* __restrict__ b2,
    const float* __restrict__ Wf1, const float* __restrict__ bf1,
    const float* __restrict__ Wf2, const float* __restrict__ bf2,
    float* __restrict__ out)
{
    __shared__ float buf[ROWS][HID];
    __shared__ float hbuf[ROWS][2 * HID];
    __shared__ float red[2][ROWS][2];
    const int l = threadIdx.x;
    const int wid = l >> 6, lane = l & 63;
    const int base = blockIdx.x * ROWS;
    #pragma unroll
    for (int r = 0; r < ROWS; ++r) buf[r][l] = agg[(size_t)(base + r) * HID + l];
    __syncthreads();
    float acc[ROWS];
    #pragma unroll
    for (int r = 0; r < ROWS; ++r) acc[r] = 0.f;
    for (int k = 0; k < HID; ++k) {
        float w = Wo[k * HID + l];
        #pragma unroll
        for (int r = 0; r < ROWS; ++r) acc[r] = fmaf(buf[r][k], w, acc[r]);
    }
    float xl[ROWS];
    const float bol = bo[l];
    #pragma unroll
    for (int r = 0; r < ROWS; ++r) {
        float o = acc[r] + bol;
        size_t idx = (size_t)(base + r) * HID + l;
        o = fmaf(gamma[idx], o, beta[idx]);
        xl[r] = x[idx] + o;
    }
    __syncthreads();
    #pragma unroll
    for (int r = 0; r < ROWS; ++r) {
        float s1 = xl[r], s2 = xl[r] * xl[r];
        #pragma unroll
        for (int m = 1; m < 64; m <<= 1) { s1 += __shfl_xor(s1, m); s2 += __shfl_xor(s2, m); }
        if (lane == 0) { red[wid][r][0] = s1; red[wid][r][1] = s2; }
    }
    __syncthreads();
    const float g2l = g2[l], b2l = b2[l];
    #pragma unroll
    for (int r = 0; r < ROWS; ++r) {
        float s1 = red[0][r][0] + red[1][r][0];
        float s2 = red[0][r][1] + red[1][r][1];
        float mu = s1 * (1.0f / HID);
        float var = s2 * (1.0f / HID) - mu * mu;
        float rstd = rsqrtf(var + 1e-5f);
        buf[r][l] = (xl[r] - mu) * rstd * g2l + b2l;
    }
    __syncthreads();
    float f0[ROWS], f1[ROWS];
    #pragma unroll
    for (int r = 0; r < ROWS; ++r) { f0[r] = 0.f; f1[r] = 0.f; }
    for (int k = 0; k < HID; ++k) {
        float w0 = Wf1[k * 256 + l], w1 = Wf1[k * 256 + l + 128];
        #pragma unroll
        for (int r = 0; r < ROWS; ++r) {
            float xv = buf[r][k];
            f0[r] = fmaf(xv, w0, f0[r]);
            f1[r] = fmaf(xv, w1, f1[r]);
        }
    }
    const float bf1a = bf1[l], bf1b = bf1[l + 128];
    #pragma unroll
    for (int r = 0; r < ROWS; ++r) {
        hbuf[r][l] = gelu_f(f0[r] + bf1a);
        hbuf[r][l + 128] = gelu_f(f1[r] + bf1b);
    }
    __syncthreads();
    float o2[ROWS];
    #pragma unroll
    for (int r = 0; r < ROWS; ++r) o2[r] = 0.f;
    for (int k = 0; k < 2 * HID; ++k) {
        float w = Wf2[k * HID + l];
        #pragma unroll
        for (int r = 0; r < ROWS; ++r) o2[r] = fmaf(hbuf[r][k], w, o2[r]);
    }
    const float bf2l = bf2[l];
    #pragma unroll
    for (int r = 0; r < ROWS; ++r)
        out[(size_t)(base + r) * HID + l] = xl[r] + o2[r] + bf2l;
}

extern "C" void kernel_launch(void* const* d_in, const int* in_sizes, int n_in,
                              void* d_out, int out_size, void* d_ws, size_t ws_size,
                              hipStream_t stream) {
    const float* x     = (const float*)d_in[0];
    const int*   ei    = (const int*)d_in[1];
    const float* ea    = (const float*)d_in[2];
    const float* gamma = (const float*)d_in[3];
    const float* beta  = (const float*)d_in[4];
    const float* ln1_g = (const float*)d_in[5];
    const float* ln1_b = (const float*)d_in[6];
    const float* Wq    = (const float*)d_in[7];
    const float* Wk    = (const float*)d_in[8];
    const float* Wv    = (const float*)d_in[9];
    const float* Wo    = (const float*)d_in[10];
    const float* bo    = (const float*)d_in[11];
    const float* Wea1  = (const float*)d_in[12];
    const float* bea1  = (const float*)d_in[13];
    const float* Wea2  = (const float*)d_in[14];
    const float* bea2  = (const float*)d_in[15];
    const float* Weg1  = (const float*)d_in[16];
    const float* beg1  = (const float*)d_in[17];
    const float* Weg2  = (const float*)d_in[18];
    const float* beg2  = (const float*)d_in[19];
    const float* ln2_g = (const float*)d_in[20];
    const float* ln2_b = (const float*)d_in[21];
    const float* Wf1   = (const float*)d_in[22];
    const float* bf1   = (const float*)d_in[23];
    const float* Wf2   = (const float*)d_in[24];
    const float* bf2   = (const float*)d_in[25];

    float* ws = (float*)d_ws;
    float* Q      = ws;
    float* K      = Q + (size_t)N_NODES * HID;
    float* V      = K + (size_t)N_NODES * HID;
    float* logits = V + (size_t)N_NODES * HID;     // E*4 floats; becomes el in-place
    float* mbuf   = logits + (size_t)E_EDGES * 4;
    float* sbuf   = mbuf + (size_t)N_NODES * 4;
    int*   deg    = (int*)(sbuf + (size_t)N_NODES * 4);
    float* agg    = (float*)(deg + N_NODES);
    int*   rowptr = (int*)(agg + (size_t)N_NODES * HID);
    int*   wptr   = rowptr + (N_NODES + 1);
    int*   bsum   = wptr + N_NODES;
    int*   eidx   = bsum + SCAN_NB;
    int*   esrc   = eidx + E_EDGES;
    int*   pdst   = esrc + E_EDGES;

    // zero mbuf, sbuf, deg, agg (contiguous)
    hipMemsetAsync(mbuf, 0,
                   ((size_t)N_NODES * 4 * 2 + (size_t)N_NODES) * sizeof(float)
                   + (size_t)N_NODES * HID * sizeof(float),
                   stream);

    // CSR build (independent of K1/K2 chain)
    k0a_degree<<<E_EDGES / 256, 256, 0, stream>>>(ei, deg);
    k0b_scan1<<<SCAN_NB, SCAN_BS, 0, stream>>>(deg, rowptr, bsum);
    k0c_scan2<<<1, 64, 0, stream>>>(bsum);
    k0d_fixup<<<SCAN_NB, SCAN_BS, 0, stream>>>(rowptr, wptr, bsum);
    k0e_scatter<<<E_EDGES / 256, 256, 0, stream>>>(ei, wptr, eidx, esrc, pdst);

    k1_ln_qkv<<<N_NODES / ROWS, 128, 0, stream>>>(x, ln1_g, ln1_b, Wq, Wk, Wv, Q, K, V);
    k2a_qkdot<<<E_EDGES / 8, 256, 0, stream>>>(ei, Q, K, logits);
    k2b_bias_max<<<E_EDGES / 256, 256, 0, stream>>>(ei, ea, Wea1, bea1, Wea2, bea2, logits, mbuf);
    k3_exp_sum<<<E_EDGES / 256, 256, 0, stream>>>(ei, mbuf, logits, sbuf);
    k4a_gate_flush<<<E_EDGES / EB, 256, 0, stream>>>(eidx, esrc, pdst, ea,
                                                     Weg1, beg1, Weg2, beg2,
                                                     logits, sbuf, V, agg);
    k5_out<<<N_NODES / ROWS, 128, 0, stream>>>(agg, Wo, bo, gamma, beta, x,
                                               ln2_g, ln2_b, Wf1, bf1, Wf2, bf2,
                                               (float*)d_out);
}

// Round 4
// 806.074 us; speedup vs baseline: 1.5341x; 1.1921x over previous
//
#include <hip/hip_runtime.h>
#include <cmath>

#define N_NODES 50000
#define E_EDGES 800000
#define HID 128
#define HEADS 4
#define HD 32
#define EDIM 16
#define EGD 32
#define ROWS 8
#define EB 64
#define SCAN_BS 512
#define SCAN_NB ((N_NODES + SCAN_BS - 1) / SCAN_BS)

__device__ __forceinline__ float gelu_f(float z) {
    return 0.5f * z * (1.0f + erff(z * 0.7071067811865476f));
}
__device__ __forceinline__ float sigmoid_fast(float z) {
    return __builtin_amdgcn_rcpf(1.0f + __expf(-z));
}

// ---------------- K1: LN1 + QKV projection (8 rows / 128-thread block) ----------------
__global__ void __launch_bounds__(128) k1_ln_qkv(
    const float* __restrict__ x, const float* __restrict__ g1, const float* __restrict__ b1,
    const float* __restrict__ Wq, const float* __restrict__ Wk, const float* __restrict__ Wv,
    float* __restrict__ Q, float* __restrict__ K, float* __restrict__ V)
{
    __shared__ float xn[ROWS][HID];
    __shared__ float red[2][ROWS][2];
    const int l = threadIdx.x;
    const int wid = l >> 6, lane = l & 63;
    const int base = blockIdx.x * ROWS;
    float xv[ROWS];
    #pragma unroll
    for (int r = 0; r < ROWS; ++r) xv[r] = x[(size_t)(base + r) * HID + l];
    #pragma unroll
    for (int r = 0; r < ROWS; ++r) {
        float s1 = xv[r], s2 = xv[r] * xv[r];
        #pragma unroll
        for (int m = 1; m < 64; m <<= 1) { s1 += __shfl_xor(s1, m); s2 += __shfl_xor(s2, m); }
        if (lane == 0) { red[wid][r][0] = s1; red[wid][r][1] = s2; }
    }
    __syncthreads();
    const float gl = g1[l], bl = b1[l];
    #pragma unroll
    for (int r = 0; r < ROWS; ++r) {
        float s1 = red[0][r][0] + red[1][r][0];
        float s2 = red[0][r][1] + red[1][r][1];
        float mu = s1 * (1.0f / HID);
        float var = s2 * (1.0f / HID) - mu * mu;
        float rstd = rsqrtf(var + 1e-5f);
        xn[r][l] = (xv[r] - mu) * rstd * gl + bl;
    }
    __syncthreads();
    float aq[ROWS], ak[ROWS], av[ROWS];
    #pragma unroll
    for (int r = 0; r < ROWS; ++r) { aq[r] = 0.f; ak[r] = 0.f; av[r] = 0.f; }
    for (int k = 0; k < HID; ++k) {
        float wq = Wq[k * HID + l], wk = Wk[k * HID + l], wv = Wv[k * HID + l];
        #pragma unroll
        for (int r = 0; r < ROWS; ++r) {
            float xr = xn[r][k];
            aq[r] = fmaf(xr, wq, aq[r]);
            ak[r] = fmaf(xr, wk, ak[r]);
            av[r] = fmaf(xr, wv, av[r]);
        }
    }
    #pragma unroll
    for (int r = 0; r < ROWS; ++r) {
        Q[(size_t)(base + r) * HID + l] = aq[r];
        K[(size_t)(base + r) * HID + l] = ak[r];
        V[(size_t)(base + r) * HID + l] = av[r];
    }
}

// ---------------- CSR build ----------------
__global__ void __launch_bounds__(256) k0a_degree(
    const int* __restrict__ ei, int* __restrict__ deg)
{
    const int e = blockIdx.x * 256 + threadIdx.x;
    atomicAdd(deg + ei[E_EDGES + e], 1);
}

__global__ void __launch_bounds__(SCAN_BS) k0b_scan1(
    const int* __restrict__ deg, int* __restrict__ rowptr, int* __restrict__ bsum)
{
    __shared__ int sm[SCAN_BS];
    const int t = threadIdx.x;
    const int i = blockIdx.x * SCAN_BS + t;
    const int v = (i < N_NODES) ? deg[i] : 0;
    sm[t] = v;
    __syncthreads();
    #pragma unroll
    for (int off = 1; off < SCAN_BS; off <<= 1) {
        int add = (t >= off) ? sm[t - off] : 0;
        __syncthreads();
        sm[t] += add;
        __syncthreads();
    }
    if (i < N_NODES) rowptr[i] = sm[t] - v;
    if (t == SCAN_BS - 1) bsum[blockIdx.x] = sm[t];
}

__global__ void __launch_bounds__(128) k0c_scan2(int* __restrict__ bsum)
{
    __shared__ int sm[128];
    const int t = threadIdx.x;
    const int v = (t < SCAN_NB) ? bsum[t] : 0;
    sm[t] = v;
    __syncthreads();
    #pragma unroll
    for (int off = 1; off < 128; off <<= 1) {
        int add = (t >= off) ? sm[t - off] : 0;
        __syncthreads();
        sm[t] += add;
        __syncthreads();
    }
    if (t < SCAN_NB) bsum[t] = sm[t] - v; // exclusive
}

__global__ void __launch_bounds__(SCAN_BS) k0d_fixup(
    int* __restrict__ rowptr, int* __restrict__ wptr, const int* __restrict__ bsum)
{
    const int i = blockIdx.x * SCAN_BS + threadIdx.x;
    if (i < N_NODES) {
        int r = rowptr[i] + bsum[blockIdx.x];
        rowptr[i] = r;
        wptr[i] = r;
    }
    if (i == 0) rowptr[N_NODES] = E_EDGES;
}

__global__ void __launch_bounds__(256) k0e_scatter(
    const int* __restrict__ ei, int* __restrict__ wptr,
    int* __restrict__ eidx, int* __restrict__ esrc, int* __restrict__ pdst)
{
    const int e = blockIdx.x * 256 + threadIdx.x;
    const int d = ei[E_EDGES + e];
    const int pos = atomicAdd(wptr + d, 1);
    eidx[pos] = e;
    esrc[pos] = ei[e];
    pdst[pos] = d;
}

// ---------------- K2: QK^T dot + edge-bias MLP + atomicMax (CSR p-order) ----------------
__global__ void __launch_bounds__(256) k2_fused(
    const int* __restrict__ eidx, const int* __restrict__ esrc, const int* __restrict__ pdst,
    const float* __restrict__ Q, const float* __restrict__ K, const float* __restrict__ ea,
    const float* __restrict__ Wea1, const float* __restrict__ bea1,
    const float* __restrict__ Wea2, const float* __restrict__ bea2,
    float* __restrict__ logits, float* __restrict__ mbuf)
{
    const int t = threadIdx.x;
    const int p = (blockIdx.x * 256 + t) >> 5;
    const int s = t & 31;
    const int e = eidx[p];
    const int src = esrc[p];
    const int dst = pdst[p];
    // QK dot: lane s covers float4 slot s; head = s>>3
    float4 q = ((const float4*)(Q + (size_t)dst * HID))[s];
    float4 k = ((const float4*)(K + (size_t)src * HID))[s];
    float pr = q.x * k.x + q.y * k.y + q.z * k.z + q.w * k.w;
    pr += __shfl_xor(pr, 1);
    pr += __shfl_xor(pr, 2);
    pr += __shfl_xor(pr, 4);
    // bias MLP: lane j = s computes hidden unit j
    const float4* eap = (const float4*)(ea + (size_t)e * EDIM);
    float4 a0 = eap[0], a1 = eap[1], a2 = eap[2], a3 = eap[3];
    float h = bea1[s];
    h = fmaf(a0.x, Wea1[0 * EGD + s], h);  h = fmaf(a0.y, Wea1[1 * EGD + s], h);
    h = fmaf(a0.z, Wea1[2 * EGD + s], h);  h = fmaf(a0.w, Wea1[3 * EGD + s], h);
    h = fmaf(a1.x, Wea1[4 * EGD + s], h);  h = fmaf(a1.y, Wea1[5 * EGD + s], h);
    h = fmaf(a1.z, Wea1[6 * EGD + s], h);  h = fmaf(a1.w, Wea1[7 * EGD + s], h);
    h = fmaf(a2.x, Wea1[8 * EGD + s], h);  h = fmaf(a2.y, Wea1[9 * EGD + s], h);
    h = fmaf(a2.z, Wea1[10 * EGD + s], h); h = fmaf(a2.w, Wea1[11 * EGD + s], h);
    h = fmaf(a3.x, Wea1[12 * EGD + s], h); h = fmaf(a3.y, Wea1[13 * EGD + s], h);
    h = fmaf(a3.z, Wea1[14 * EGD + s], h); h = fmaf(a3.w, Wea1[15 * EGD + s], h);
    h = gelu_f(h);
    const float4 w2 = ((const float4*)Wea2)[s]; // Wea2[s][0..4]
    float b0 = h * w2.x, b1 = h * w2.y, b2 = h * w2.z, b3 = h * w2.w;
    #pragma unroll
    for (int off = 1; off < 32; off <<= 1) {
        b0 += __shfl_xor(b0, off);
        b1 += __shfl_xor(b1, off);
        b2 += __shfl_xor(b2, off);
        b3 += __shfl_xor(b3, off);
    }
    // collect head dot for lanes 0..3 of each half
    const float dv = __shfl(pr, (t & 32) + ((s & 3) << 3));
    if (s < 4) {
        const float bias = (s == 0) ? b0 : (s == 1) ? b1 : (s == 2) ? b2 : b3;
        const float lg = dv * 0.17677669529663689f + bias + bea2[s];
        logits[(size_t)p * 4 + s] = lg;
        if (lg > 0.f) atomicMax((int*)mbuf + (size_t)dst * 4 + s, __float_as_int(lg));
    }
}

// ---------------- K3: el = exp(logit - m); segmented-scan + one atomic per run ----------------
__global__ void __launch_bounds__(256) k3_exp_sum(
    const int* __restrict__ pdst, const float* __restrict__ mbuf,
    float* __restrict__ logits /* in: logits, out: el (p-order) */, float* __restrict__ sbuf)
{
    const int p = blockIdx.x * 256 + threadIdx.x;
    const int lane = threadIdx.x & 63;
    const int d = pdst[p];
    float4 lg = *(const float4*)(logits + (size_t)p * 4);
    const float4 mv = *(const float4*)(mbuf + (size_t)d * 4);
    lg.x = __expf(lg.x - mv.x);
    lg.y = __expf(lg.y - mv.y);
    lg.z = __expf(lg.z - mv.z);
    lg.w = __expf(lg.w - mv.w);
    *(float4*)(logits + (size_t)p * 4) = lg;
    // wave-level segmented inclusive scan keyed by d (dst sorted within CSR)
    float4 v = lg;
    #pragma unroll
    for (int off = 1; off < 64; off <<= 1) {
        const int du = __shfl_up(d, off);
        const float ux = __shfl_up(v.x, off);
        const float uy = __shfl_up(v.y, off);
        const float uz = __shfl_up(v.z, off);
        const float uw = __shfl_up(v.w, off);
        if (lane >= off && du == d) { v.x += ux; v.y += uy; v.z += uz; v.w += uw; }
    }
    const int dn = __shfl_down(d, 1);
    if (lane == 63 || dn != d) {
        atomicAdd(sbuf + (size_t)d * 4 + 0, v.x);
        atomicAdd(sbuf + (size_t)d * 4 + 1, v.y);
        atomicAdd(sbuf + (size_t)d * 4 + 2, v.z);
        atomicAdd(sbuf + (size_t)d * 4 + 3, v.w);
    }
}

// ---------------- K4a: gate MLP (swizzled LDS) + attn-V fold + run-length flush ----------------
__global__ void __launch_bounds__(256) k4a_gate_flush(
    const int* __restrict__ eidx, const int* __restrict__ esrc, const int* __restrict__ pdst,
    const float* __restrict__ ea,
    const float* __restrict__ Weg1, const float* __restrict__ beg1,
    const float* __restrict__ Weg2, const float* __restrict__ beg2,
    const float* __restrict__ el, const float* __restrict__ sbuf,
    const float* __restrict__ V, float* __restrict__ agg)
{
    __shared__ float hsm[EB][EGD];        // accessed as swizzled float4 slots
    __shared__ float w1sm[EDIM * EGD];
    const int t = threadIdx.x;
    const int p0 = blockIdx.x * EB;

    w1sm[t] = Weg1[t];
    w1sm[t + 256] = Weg1[t + 256];
    __syncthreads();

    // ---- phase 1: layer-1; thread = (edge slot, 8 hidden units); swizzled b128 stores ----
    {
        const int s = t & 63;
        const int jg = t >> 6; // 0..3 -> hidden units jg*8..jg*8+8
        const int e = eidx[p0 + s];
        const float4* eap = (const float4*)(ea + (size_t)e * EDIM);
        float4 v0 = eap[0], v1 = eap[1], v2 = eap[2], v3 = eap[3];
        float a[EDIM] = {v0.x, v0.y, v0.z, v0.w, v1.x, v1.y, v1.z, v1.w,
                         v2.x, v2.y, v2.z, v2.w, v3.x, v3.y, v3.z, v3.w};
        float h[8];
        #pragma unroll
        for (int jo = 0; jo < 8; ++jo) h[jo] = beg1[jg * 8 + jo];
        #pragma unroll
        for (int k = 0; k < EDIM; ++k) {
            const float4 w0 = *(const float4*)&w1sm[k * EGD + jg * 8];
            const float4 w1 = *(const float4*)&w1sm[k * EGD + jg * 8 + 4];
            h[0] = fmaf(a[k], w0.x, h[0]); h[1] = fmaf(a[k], w0.y, h[1]);
            h[2] = fmaf(a[k], w0.z, h[2]); h[3] = fmaf(a[k], w0.w, h[3]);
            h[4] = fmaf(a[k], w1.x, h[4]); h[5] = fmaf(a[k], w1.y, h[5]);
            h[6] = fmaf(a[k], w1.z, h[6]); h[7] = fmaf(a[k], w1.w, h[7]);
        }
        float4 o0, o1;
        o0.x = gelu_f(h[0]); o0.y = gelu_f(h[1]); o0.z = gelu_f(h[2]); o0.w = gelu_f(h[3]);
        o1.x = gelu_f(h[4]); o1.y = gelu_f(h[5]); o1.z = gelu_f(h[6]); o1.w = gelu_f(h[7]);
        float4* hsm4 = (float4*)hsm;
        const int sw = s & 7; // XOR swizzle: each 8-lane group covers all 32 banks
        hsm4[s * 8 + ((jg * 2) ^ sw)] = o0;
        hsm4[s * 8 + ((jg * 2 + 1) ^ sw)] = o1;
    }
    __syncthreads();

    // ---- phase 2: layer-2 (pure FMA, broadcast LDS reads) + attn fold + flush ----
    const int w = t >> 6, l = t & 63;
    float wa[EGD], wb[EGD];
    #pragma unroll
    for (int jj = 0; jj < EGD; ++jj) {
        wa[jj] = Weg2[jj * HID + l];
        wb[jj] = Weg2[jj * HID + 64 + l];
    }
    const float b20 = beg2[l], b21 = beg2[l + 64];
    const int h0 = l >> 5, h1c = 2 + (l >> 5);
    const int sbase = w << 4;
    int cur = pdst[p0 + sbase];
    float inv0 = __builtin_amdgcn_rcpf(sbuf[(size_t)cur * 4 + h0] + 1e-10f);
    float inv1 = __builtin_amdgcn_rcpf(sbuf[(size_t)cur * 4 + h1c] + 1e-10f);
    float acc0 = 0.f, acc1 = 0.f;
    const float4* hsm4 = (const float4*)hsm;
    for (int s = sbase; s < sbase + 16; ++s) {
        const int p = p0 + s;
        const int src = esrc[p];
        const int d = pdst[p];
        if (d != cur) { // wave-uniform branch
            atomicAdd(agg + (size_t)cur * HID + l, acc0);
            atomicAdd(agg + (size_t)cur * HID + 64 + l, acc1);
            acc0 = 0.f; acc1 = 0.f;
            cur = d;
            inv0 = __builtin_amdgcn_rcpf(sbuf[(size_t)cur * 4 + h0] + 1e-10f);
            inv1 = __builtin_amdgcn_rcpf(sbuf[(size_t)cur * 4 + h1c] + 1e-10f);
        }
        const int sw = s & 7;
        float g0 = b20, g1 = b21;
        #pragma unroll
        for (int jq = 0; jq < 8; ++jq) {
            const float4 h4 = hsm4[s * 8 + (jq ^ sw)]; // uniform addr -> broadcast
            const int jj = jq * 4;
            g0 = fmaf(h4.x, wa[jj + 0], g0); g1 = fmaf(h4.x, wb[jj + 0], g1);
            g0 = fmaf(h4.y, wa[jj + 1], g0); g1 = fmaf(h4.y, wb[jj + 1], g1);
            g0 = fmaf(h4.z, wa[jj + 2], g0); g1 = fmaf(h4.z, wb[jj + 2], g1);
            g0 = fmaf(h4.w, wa[jj + 3], g0); g1 = fmaf(h4.w, wb[jj + 3], g1);
        }
        g0 = sigmoid_fast(g0);
        g1 = sigmoid_fast(g1);
        const float at0 = el[(size_t)p * 4 + h0] * inv0;
        const float at1 = el[(size_t)p * 4 + h1c] * inv1;
        acc0 = fmaf(at0 * g0, V[(size_t)src * HID + l], acc0);
        acc1 = fmaf(at1 * g1, V[(size_t)src * HID + 64 + l], acc1);
    }
    atomicAdd(agg + (size_t)cur * HID + l, acc0);
    atomicAdd(agg + (size_t)cur * HID + 64 + l, acc1);
}

// ---------------- K5: Wo + FiLM + residual + LN2 + FFN + residual ----------------
__global__ void __launch_bounds__(128) k5_out(
    const float* __restrict__ agg, const float* __restrict__ Wo, const float* __restrict__ bo,
    const float* __restrict__ gamma, const float* __restrict__ beta,
    const float* __restrict__ x,
    const float* __restrict__ g2, const float* __restrict__ b2,
    const float* __restrict__ Wf1, const float* __restrict__ bf1,
    const float* __restrict__ Wf2, const float* __restrict__ bf2,
    float* __restrict__ out)
{
    __shared__ float buf[ROWS][HID];
    __shared__ float hbuf[ROWS][2 * HID];
    __shared__ float red[2][ROWS][2];
    const int l = threadIdx.x;
    const int wid = l >> 6, lane = l & 63;
    const int base = blockIdx.x * ROWS;
    #pragma unroll
    for (int r = 0; r < ROWS; ++r) buf[r][l] = agg[(size_t)(base + r) * HID + l];
    __syncthreads();
    float acc[ROWS];
    #pragma unroll
    for (int r = 0; r < ROWS; ++r) acc[r] = 0.f;
    for (int k = 0; k < HID; ++k) {
        float w = Wo[k * HID + l];
        #pragma unroll
        for (int r = 0; r < ROWS; ++r) acc[r] = fmaf(buf[r][k], w, acc[r]);
    }
    float xl[ROWS];
    const float bol = bo[l];
    #pragma unroll
    for (int r = 0; r < ROWS; ++r) {
        float o = acc[r] + bol;
        size_t idx = (size_t)(base + r) * HID + l;
        o = fmaf(gamma[idx], o, beta[idx]);
        xl[r] = x[idx] + o;
    }
    __syncthreads();
    #pragma unroll
    for (int r = 0; r < ROWS; ++r) {
        float s1 = xl[r], s2 = xl[r] * xl[r];
        #pragma unroll
        for (int m = 1; m < 64; m <<= 1) { s1 += __shfl_xor(s1, m); s2 += __shfl_xor(s2, m); }
        if (lane == 0) { red[wid][r][0] = s1; red[wid][r][1] = s2; }
    }
    __syncthreads();
    const float g2l = g2[l], b2l = b2[l];
    #pragma unroll
    for (int r = 0; r < ROWS; ++r) {
        float s1 = red[0][r][0] + red[1][r][0];
        float s2 = red[0][r][1] + red[1][r][1];
        float mu = s1 * (1.0f / HID);
        float var = s2 * (1.0f / HID) - mu * mu;
        float rstd = rsqrtf(var + 1e-5f);
        buf[r][l] = (xl[r] - mu) * rstd * g2l + b2l;
    }
    __syncthreads();
    float f0[ROWS], f1[ROWS];
    #pragma unroll
    for (int r = 0; r < ROWS; ++r) { f0[r] = 0.f; f1[r] = 0.f; }
    for (int k = 0; k < HID; ++k) {
        float w0 = Wf1[k * 256 + l], w1 = Wf1[k * 256 + l + 128];
        #pragma unroll
        for (int r = 0; r < ROWS; ++r) {
            float xv = buf[r][k];
            f0[r] = fmaf(xv, w0, f0[r]);
            f1[r] = fmaf(xv, w1, f1[r]);
        }
    }
    const float bf1a = bf1[l], bf1b = bf1[l + 128];
    #pragma unroll
    for (int r = 0; r < ROWS; ++r) {
        hbuf[r][l] = gelu_f(f0[r] + bf1a);
        hbuf[r][l + 128] = gelu_f(f1[r] + bf1b);
    }
    __syncthreads();
    float o2[ROWS];
    #pragma unroll
    for (int r = 0; r < ROWS; ++r) o2[r] = 0.f;
    for (int k = 0; k < 2 * HID; ++k) {
        float w = Wf2[k * HID + l];
        #pragma unroll
        for (int r = 0; r < ROWS; ++r) o2[r] = fmaf(hbuf[r][k], w, o2[r]);
    }
    const float bf2l = bf2[l];
    #pragma unroll
    for (int r = 0; r < ROWS; ++r)
        out[(size_t)(base + r) * HID + l] = xl[r] + o2[r] + bf2l;
}

extern "C" void kernel_launch(void* const* d_in, const int* in_sizes, int n_in,
                              void* d_out, int out_size, void* d_ws, size_t ws_size,
                              hipStream_t stream) {
    const float* x     = (const float*)d_in[0];
    const int*   ei    = (const int*)d_in[1];
    const float* ea    = (const float*)d_in[2];
    const float* gamma = (const float*)d_in[3];
    const float* beta  = (const float*)d_in[4];
    const float* ln1_g = (const float*)d_in[5];
    const float* ln1_b = (const float*)d_in[6];
    const float* Wq    = (const float*)d_in[7];
    const float* Wk    = (const float*)d_in[8];
    const float* Wv    = (const float*)d_in[9];
    const float* Wo    = (const float*)d_in[10];
    const float* bo    = (const float*)d_in[11];
    const float* Wea1  = (const float*)d_in[12];
    const float* bea1  = (const float*)d_in[13];
    const float* Wea2  = (const float*)d_in[14];
    const float* bea2  = (const float*)d_in[15];
    const float* Weg1  = (const float*)d_in[16];
    const float* beg1  = (const float*)d_in[17];
    const float* Weg2  = (const float*)d_in[18];
    const float* beg2  = (const float*)d_in[19];
    const float* ln2_g = (const float*)d_in[20];
    const float* ln2_b = (const float*)d_in[21];
    const float* Wf1   = (const float*)d_in[22];
    const float* bf1   = (const float*)d_in[23];
    const float* Wf2   = (const float*)d_in[24];
    const float* bf2   = (const float*)d_in[25];

    float* ws = (float*)d_ws;
    float* Q      = ws;
    float* K      = Q + (size_t)N_NODES * HID;
    float* V      = K + (size_t)N_NODES * HID;
    float* logits = V + (size_t)N_NODES * HID;     // E*4 floats, p-order; becomes el in-place
    float* mbuf   = logits + (size_t)E_EDGES * 4;
    float* sbuf   = mbuf + (size_t)N_NODES * 4;
    int*   deg    = (int*)(sbuf + (size_t)N_NODES * 4);
    float* agg    = (float*)(deg + N_NODES);
    int*   rowptr = (int*)(agg + (size_t)N_NODES * HID);
    int*   wptr   = rowptr + (N_NODES + 1);
    int*   bsum   = wptr + N_NODES;
    int*   eidx   = bsum + 128;
    int*   esrc   = eidx + E_EDGES;
    int*   pdst   = esrc + E_EDGES;

    // zero mbuf, sbuf, deg, agg (contiguous)
    hipMemsetAsync(mbuf, 0,
                   ((size_t)N_NODES * 4 * 2 + (size_t)N_NODES) * sizeof(float)
                   + (size_t)N_NODES * HID * sizeof(float),
                   stream);

    // CSR build
    k0a_degree<<<E_EDGES / 256, 256, 0, stream>>>(ei, deg);
    k0b_scan1<<<SCAN_NB, SCAN_BS, 0, stream>>>(deg, rowptr, bsum);
    k0c_scan2<<<1, 128, 0, stream>>>(bsum);
    k0d_fixup<<<SCAN_NB, SCAN_BS, 0, stream>>>(rowptr, wptr, bsum);
    k0e_scatter<<<E_EDGES / 256, 256, 0, stream>>>(ei, wptr, eidx, esrc, pdst);

    k1_ln_qkv<<<N_NODES / ROWS, 128, 0, stream>>>(x, ln1_g, ln1_b, Wq, Wk, Wv, Q, K, V);
    k2_fused<<<(size_t)E_EDGES * 32 / 256, 256, 0, stream>>>(eidx, esrc, pdst, Q, K, ea,
                                                             Wea1, bea1, Wea2, bea2,
                                                             logits, mbuf);
    k3_exp_sum<<<E_EDGES / 256, 256, 0, stream>>>(pdst, mbuf, logits, sbuf);
    k4a_gate_flush<<<E_EDGES / EB, 256, 0, stream>>>(eidx, esrc, pdst, ea,
                                                     Weg1, beg1, Weg2, beg2,
                                                     logits, sbuf, V, agg);
    k5_out<<<N_NODES / ROWS, 128, 0, stream>>>(agg, Wo, bo, gamma, beta, x,
                                               ln2_g, ln2_b, Wf1, bf1, Wf2, bf2,
                                               (float*)d_out);
}

// Round 5
// 805.935 us; speedup vs baseline: 1.5344x; 1.0002x over previous
//
#include <hip/hip_runtime.h>
#include <cmath>

#define N_NODES 50000
#define E_EDGES 800000
#define HID 128
#define HEADS 4
#define HD 32
#define EDIM 16
#define EGD 32
#define ROWS 8
#define NPW 4
#define SCAN_BS 512
#define SCAN_NB ((N_NODES + SCAN_BS - 1) / SCAN_BS)

typedef __attribute__((ext_vector_type(8))) short bf16x8;
typedef __attribute__((ext_vector_type(4))) float f32x4;

__device__ __forceinline__ float gelu_f(float z) {
    return 0.5f * z * (1.0f + erff(z * 0.7071067811865476f));
}
__device__ __forceinline__ float sigmoid_fast(float z) {
    return __builtin_amdgcn_rcpf(1.0f + __expf(-z));
}
__device__ __forceinline__ short f2bf(float f) {
    unsigned u = __float_as_uint(f);
    unsigned r = u + 0x7fffu + ((u >> 16) & 1u);
    return (short)(r >> 16);
}

// ---------------- K1: LN1 + QKV projection (8 rows / 128-thread block) ----------------
__global__ void __launch_bounds__(128) k1_ln_qkv(
    const float* __restrict__ x, const float* __restrict__ g1, const float* __restrict__ b1,
    const float* __restrict__ Wq, const float* __restrict__ Wk, const float* __restrict__ Wv,
    float* __restrict__ Q, float* __restrict__ K, float* __restrict__ V)
{
    __shared__ float xn[ROWS][HID];
    __shared__ float red[2][ROWS][2];
    const int l = threadIdx.x;
    const int wid = l >> 6, lane = l & 63;
    const int base = blockIdx.x * ROWS;
    float xv[ROWS];
    #pragma unroll
    for (int r = 0; r < ROWS; ++r) xv[r] = x[(size_t)(base + r) * HID + l];
    #pragma unroll
    for (int r = 0; r < ROWS; ++r) {
        float s1 = xv[r], s2 = xv[r] * xv[r];
        #pragma unroll
        for (int m = 1; m < 64; m <<= 1) { s1 += __shfl_xor(s1, m); s2 += __shfl_xor(s2, m); }
        if (lane == 0) { red[wid][r][0] = s1; red[wid][r][1] = s2; }
    }
    __syncthreads();
    const float gl = g1[l], bl = b1[l];
    #pragma unroll
    for (int r = 0; r < ROWS; ++r) {
        float s1 = red[0][r][0] + red[1][r][0];
        float s2 = red[0][r][1] + red[1][r][1];
        float mu = s1 * (1.0f / HID);
        float var = s2 * (1.0f / HID) - mu * mu;
        float rstd = rsqrtf(var + 1e-5f);
        xn[r][l] = (xv[r] - mu) * rstd * gl + bl;
    }
    __syncthreads();
    float aq[ROWS], ak[ROWS], av[ROWS];
    #pragma unroll
    for (int r = 0; r < ROWS; ++r) { aq[r] = 0.f; ak[r] = 0.f; av[r] = 0.f; }
    for (int k = 0; k < HID; ++k) {
        float wq = Wq[k * HID + l], wk = Wk[k * HID + l], wv = Wv[k * HID + l];
        #pragma unroll
        for (int r = 0; r < ROWS; ++r) {
            float xr = xn[r][k];
            aq[r] = fmaf(xr, wq, aq[r]);
            ak[r] = fmaf(xr, wk, ak[r]);
            av[r] = fmaf(xr, wv, av[r]);
        }
    }
    #pragma unroll
    for (int r = 0; r < ROWS; ++r) {
        Q[(size_t)(base + r) * HID + l] = aq[r];
        K[(size_t)(base + r) * HID + l] = ak[r];
        V[(size_t)(base + r) * HID + l] = av[r];
    }
}

// ---------------- CSR build ----------------
__global__ void __launch_bounds__(256) k0a_degree(
    const int* __restrict__ ei, int* __restrict__ deg)
{
    const int e = blockIdx.x * 256 + threadIdx.x;
    atomicAdd(deg + ei[E_EDGES + e], 1);
}

__global__ void __launch_bounds__(SCAN_BS) k0b_scan1(
    const int* __restrict__ deg, int* __restrict__ rowptr, int* __restrict__ bsum)
{
    __shared__ int sm[SCAN_BS];
    const int t = threadIdx.x;
    const int i = blockIdx.x * SCAN_BS + t;
    const int v = (i < N_NODES) ? deg[i] : 0;
    sm[t] = v;
    __syncthreads();
    #pragma unroll
    for (int off = 1; off < SCAN_BS; off <<= 1) {
        int add = (t >= off) ? sm[t - off] : 0;
        __syncthreads();
        sm[t] += add;
        __syncthreads();
    }
    if (i < N_NODES) rowptr[i] = sm[t] - v;
    if (t == SCAN_BS - 1) bsum[blockIdx.x] = sm[t];
}

__global__ void __launch_bounds__(128) k0c_scan2(int* __restrict__ bsum)
{
    __shared__ int sm[128];
    const int t = threadIdx.x;
    const int v = (t < SCAN_NB) ? bsum[t] : 0;
    sm[t] = v;
    __syncthreads();
    #pragma unroll
    for (int off = 1; off < 128; off <<= 1) {
        int add = (t >= off) ? sm[t - off] : 0;
        __syncthreads();
        sm[t] += add;
        __syncthreads();
    }
    if (t < SCAN_NB) bsum[t] = sm[t] - v; // exclusive
}

__global__ void __launch_bounds__(SCAN_BS) k0d_fixup(
    int* __restrict__ rowptr, int* __restrict__ wptr, const int* __restrict__ bsum)
{
    const int i = blockIdx.x * SCAN_BS + threadIdx.x;
    if (i < N_NODES) {
        int r = rowptr[i] + bsum[blockIdx.x];
        rowptr[i] = r;
        wptr[i] = r;
    }
    if (i == 0) rowptr[N_NODES] = E_EDGES;
}

__global__ void __launch_bounds__(256) k0e_scatter(
    const int* __restrict__ ei, int* __restrict__ wptr,
    int* __restrict__ eidx, int* __restrict__ esrc, int* __restrict__ pdst)
{
    const int e = blockIdx.x * 256 + threadIdx.x;
    const int d = ei[E_EDGES + e];
    const int pos = atomicAdd(wptr + d, 1);
    eidx[pos] = e;
    esrc[pos] = ei[e];
    pdst[pos] = d;
}

// ---------------- K2: QK^T dot + edge-bias MLP + atomicMax (CSR p-order) ----------------
__global__ void __launch_bounds__(256) k2_fused(
    const int* __restrict__ eidx, const int* __restrict__ esrc, const int* __restrict__ pdst,
    const float* __restrict__ Q, const float* __restrict__ K, const float* __restrict__ ea,
    const float* __restrict__ Wea1, const float* __restrict__ bea1,
    const float* __restrict__ Wea2, const float* __restrict__ bea2,
    float* __restrict__ logits, float* __restrict__ mbuf)
{
    const int t = threadIdx.x;
    const int p = (blockIdx.x * 256 + t) >> 5;
    const int s = t & 31;
    const int e = eidx[p];
    const int src = esrc[p];
    const int dst = pdst[p];
    float4 q = ((const float4*)(Q + (size_t)dst * HID))[s];
    float4 k = ((const float4*)(K + (size_t)src * HID))[s];
    float pr = q.x * k.x + q.y * k.y + q.z * k.z + q.w * k.w;
    pr += __shfl_xor(pr, 1);
    pr += __shfl_xor(pr, 2);
    pr += __shfl_xor(pr, 4);
    const float4* eap = (const float4*)(ea + (size_t)e * EDIM);
    float4 a0 = eap[0], a1 = eap[1], a2 = eap[2], a3 = eap[3];
    float h = bea1[s];
    h = fmaf(a0.x, Wea1[0 * EGD + s], h);  h = fmaf(a0.y, Wea1[1 * EGD + s], h);
    h = fmaf(a0.z, Wea1[2 * EGD + s], h);  h = fmaf(a0.w, Wea1[3 * EGD + s], h);
    h = fmaf(a1.x, Wea1[4 * EGD + s], h);  h = fmaf(a1.y, Wea1[5 * EGD + s], h);
    h = fmaf(a1.z, Wea1[6 * EGD + s], h);  h = fmaf(a1.w, Wea1[7 * EGD + s], h);
    h = fmaf(a2.x, Wea1[8 * EGD + s], h);  h = fmaf(a2.y, Wea1[9 * EGD + s], h);
    h = fmaf(a2.z, Wea1[10 * EGD + s], h); h = fmaf(a2.w, Wea1[11 * EGD + s], h);
    h = fmaf(a3.x, Wea1[12 * EGD + s], h); h = fmaf(a3.y, Wea1[13 * EGD + s], h);
    h = fmaf(a3.z, Wea1[14 * EGD + s], h); h = fmaf(a3.w, Wea1[15 * EGD + s], h);
    h = gelu_f(h);
    const float4 w2 = ((const float4*)Wea2)[s];
    float b0 = h * w2.x, b1 = h * w2.y, b2 = h * w2.z, b3 = h * w2.w;
    #pragma unroll
    for (int off = 1; off < 32; off <<= 1) {
        b0 += __shfl_xor(b0, off);
        b1 += __shfl_xor(b1, off);
        b2 += __shfl_xor(b2, off);
        b3 += __shfl_xor(b3, off);
    }
    const float dv = __shfl(pr, (t & 32) + ((s & 3) << 3));
    if (s < 4) {
        const float bias = (s == 0) ? b0 : (s == 1) ? b1 : (s == 2) ? b2 : b3;
        const float lg = dv * 0.17677669529663689f + bias + bea2[s];
        logits[(size_t)p * 4 + s] = lg;
        if (lg > 0.f) atomicMax((int*)mbuf + (size_t)dst * 4 + s, __float_as_int(lg));
    }
}

// ---------------- K3: el = exp(logit - m); segmented-scan + one atomic per run ----------------
__global__ void __launch_bounds__(256) k3_exp_sum(
    const int* __restrict__ pdst, const float* __restrict__ mbuf,
    float* __restrict__ logits /* in: logits, out: el (p-order) */, float* __restrict__ sbuf)
{
    const int p = blockIdx.x * 256 + threadIdx.x;
    const int lane = threadIdx.x & 63;
    const int d = pdst[p];
    float4 lg = *(const float4*)(logits + (size_t)p * 4);
    const float4 mv = *(const float4*)(mbuf + (size_t)d * 4);
    lg.x = __expf(lg.x - mv.x);
    lg.y = __expf(lg.y - mv.y);
    lg.z = __expf(lg.z - mv.z);
    lg.w = __expf(lg.w - mv.w);
    *(float4*)(logits + (size_t)p * 4) = lg;
    float4 v = lg;
    #pragma unroll
    for (int off = 1; off < 64; off <<= 1) {
        const int du = __shfl_up(d, off);
        const float ux = __shfl_up(v.x, off);
        const float uy = __shfl_up(v.y, off);
        const float uz = __shfl_up(v.z, off);
        const float uw = __shfl_up(v.w, off);
        if (lane >= off && du == d) { v.x += ux; v.y += uy; v.z += uz; v.w += uw; }
    }
    const int dn = __shfl_down(d, 1);
    if (lane == 63 || dn != d) {
        atomicAdd(sbuf + (size_t)d * 4 + 0, v.x);
        atomicAdd(sbuf + (size_t)d * 4 + 1, v.y);
        atomicAdd(sbuf + (size_t)d * 4 + 2, v.z);
        atomicAdd(sbuf + (size_t)d * 4 + 3, v.w);
    }
}

// ---------------- K4: MFMA gate MLP + attn-V fold; 1 wave = 4 nodes, no atomics ----------------
// Fragment conventions (consistent-k trick): A: row=lane&15, k=(lane>>4)*8+j.
// B: col=lane&15, k=(lane>>4)*8+j. C/D (verified): col=lane&15, row=(lane>>4)*4+reg.
__global__ void __launch_bounds__(256) k4_mfma(
    const int* __restrict__ rowptr, const int* __restrict__ eidx, const int* __restrict__ esrc,
    const float* __restrict__ ea,
    const float* __restrict__ Weg1, const float* __restrict__ beg1,
    const float* __restrict__ Weg2, const float* __restrict__ beg2,
    const float* __restrict__ el, const float* __restrict__ sbuf,
    const float* __restrict__ V, float* __restrict__ agg)
{
    __shared__ short h_lds[4][16 * EGD];      // per-wave [edge][hidden] bf16
    __shared__ float attn_lds[4][16][4];      // per-wave [edge][head]
    const int t = threadIdx.x;
    const int wid = t >> 6, l = t & 63;
    const int q = l >> 4, c15 = l & 15;

    // B2 fragments: Weg2[k = q*8+j][col = tt*16 + c15]
    bf16x8 b2[8];
    #pragma unroll
    for (int tt = 0; tt < 8; ++tt) {
        #pragma unroll
        for (int j = 0; j < 8; ++j)
            b2[tt][j] = f2bf(Weg2[(q * 8 + j) * HID + tt * 16 + c15]);
    }
    // B1 fragments (K padded 16->32: quarters 2,3 are zero)
    bf16x8 b1f[2];
    #pragma unroll
    for (int n = 0; n < 2; ++n) {
        #pragma unroll
        for (int j = 0; j < 8; ++j)
            b1f[n][j] = (q < 2) ? f2bf(Weg1[(q * 8 + j) * EGD + n * 16 + c15]) : (short)0;
    }
    const float b1c0 = beg1[c15], b1c1 = beg1[16 + c15];
    float bg2[8];
    #pragma unroll
    for (int tt = 0; tt < 8; ++tt) bg2[tt] = beg2[tt * 16 + c15];

    const f32x4 zc = {0.f, 0.f, 0.f, 0.f};
    const int n0 = (blockIdx.x * 4 + wid) * NPW;

    for (int ni = 0; ni < NPW; ++ni) {
        const int n = n0 + ni;
        if (n >= N_NODES) break;
        const int pstart = rowptr[n], pend = rowptr[n + 1];
        const float invh = __builtin_amdgcn_rcpf(sbuf[(size_t)n * 4 + (l & 3)] + 1e-10f);
        float accv[8];
        #pragma unroll
        for (int tt = 0; tt < 8; ++tt) accv[tt] = 0.f;

        for (int pc = pstart; pc < pend; pc += 16) {
            const int cnt = min(16, pend - pc);
            // ---- stage: lanes q<2 load A1 (ea), lanes q>=2 stage attn ----
            bf16x8 a1 = {0, 0, 0, 0, 0, 0, 0, 0};
            if (q < 2) {
                if (c15 < cnt) {
                    const int e = eidx[pc + c15];
                    const float4 u0 = *(const float4*)(ea + (size_t)e * EDIM + q * 8);
                    const float4 u1 = *(const float4*)(ea + (size_t)e * EDIM + q * 8 + 4);
                    a1[0] = f2bf(u0.x); a1[1] = f2bf(u0.y); a1[2] = f2bf(u0.z); a1[3] = f2bf(u0.w);
                    a1[4] = f2bf(u1.x); a1[5] = f2bf(u1.y); a1[6] = f2bf(u1.z); a1[7] = f2bf(u1.w);
                }
            } else {
                const int idx2 = l & 31;
                const int slot = idx2 >> 2, head = idx2 & 3;
                float v0 = 0.f, v1 = 0.f;
                if (slot < cnt)     v0 = el[(size_t)(pc + slot) * 4 + head] * invh;
                if (slot + 8 < cnt) v1 = el[(size_t)(pc + slot + 8) * 4 + head] * invh;
                attn_lds[wid][slot][head] = v0;
                attn_lds[wid][slot + 8][head] = v1;
            }
            // ---- layer-1 MFMA: h_pre = ea @ Weg1 ----
            f32x4 c0 = __builtin_amdgcn_mfma_f32_16x16x32_bf16(a1, b1f[0], zc, 0, 0, 0);
            f32x4 c1 = __builtin_amdgcn_mfma_f32_16x16x32_bf16(a1, b1f[1], zc, 0, 0, 0);
            #pragma unroll
            for (int r = 0; r < 4; ++r) {
                h_lds[wid][(q * 4 + r) * EGD + c15]      = f2bf(gelu_f(c0[r] + b1c0));
                h_lds[wid][(q * 4 + r) * EGD + 16 + c15] = f2bf(gelu_f(c1[r] + b1c1));
            }
            asm volatile("s_waitcnt lgkmcnt(0)" ::: "memory");
            __builtin_amdgcn_sched_barrier(0);
            // ---- gather A2 / attn / src ----
            const bf16x8 a2 = *(const bf16x8*)&h_lds[wid][c15 * EGD + q * 8];
            f32x4 at[4];
            int srcr[4];
            #pragma unroll
            for (int r = 0; r < 4; ++r) {
                at[r] = *(const f32x4*)&attn_lds[wid][q * 4 + r][0];
                srcr[r] = (q * 4 + r < cnt) ? esrc[pc + q * 4 + r] : 0;
            }
            // ---- layer-2 MFMA: G = h @ Weg2 ----
            f32x4 g[8];
            #pragma unroll
            for (int tt = 0; tt < 8; ++tt)
                g[tt] = __builtin_amdgcn_mfma_f32_16x16x32_bf16(a2, b2[tt], zc, 0, 0, 0);
            // ---- fold: accv[tt] += attn * sigmoid(G + b) * V[src][col] ----
            #pragma unroll
            for (int tt = 0; tt < 8; ++tt) {
                #pragma unroll
                for (int r = 0; r < 4; ++r) {
                    const float sg = sigmoid_fast(g[tt][r] + bg2[tt]);
                    const float aw = (tt < 2) ? at[r][0] : (tt < 4) ? at[r][1]
                                   : (tt < 6) ? at[r][2] : at[r][3];
                    const float vv = V[(size_t)srcr[r] * HID + tt * 16 + c15];
                    accv[tt] = fmaf(aw * sg, vv, accv[tt]);
                }
            }
        }
        // ---- cross-quarter reduce + direct store (no atomics) ----
        #pragma unroll
        for (int tt = 0; tt < 8; ++tt) {
            accv[tt] += __shfl_xor(accv[tt], 16);
            accv[tt] += __shfl_xor(accv[tt], 32);
        }
        agg[(size_t)n * HID + (2 * q) * 16 + c15]     = accv[2 * q];
        agg[(size_t)n * HID + (2 * q + 1) * 16 + c15] = accv[2 * q + 1];
    }
}

// ---------------- K5: Wo + FiLM + residual + LN2 + FFN + residual ----------------
__global__ void __launch_bounds__(128) k5_out(
    const float* __restrict__ agg, const float* __restrict__ Wo, const float* __restrict__ bo,
    const float* __restrict__ gamma, const float* __restrict__ beta,
    const float* __restrict__ x,
    const float* __restrict__ g2, const float* __restrict__ b2,
    const float* __restrict__ Wf1, const float* __restrict__ bf1,
    const float* __restrict__ Wf2, const float* __restrict__ bf2,
    float* __restrict__ out)
{
    __shared__ float buf[ROWS][HID];
    __shared__ float hbuf[ROWS][2 * HID];
    __shared__ float red[2][ROWS][2];
    const int l = threadIdx.x;
    const int wid = l >> 6, lane = l & 63;
    const int base = blockIdx.x * ROWS;
    #pragma unroll
    for (int r = 0; r < ROWS; ++r) buf[r][l] = agg[(size_t)(base + r) * HID + l];
    __syncthreads();
    float acc[ROWS];
    #pragma unroll
    for (int r = 0; r < ROWS; ++r) acc[r] = 0.f;
    for (int k = 0; k < HID; ++k) {
        float w = Wo[k * HID + l];
        #pragma unroll
        for (int r = 0; r < ROWS; ++r) acc[r] = fmaf(buf[r][k], w, acc[r]);
    }
    float xl[ROWS];
    const float bol = bo[l];
    #pragma unroll
    for (int r = 0; r < ROWS; ++r) {
        float o = acc[r] + bol;
        size_t idx = (size_t)(base + r) * HID + l;
        o = fmaf(gamma[idx], o, beta[idx]);
        xl[r] = x[idx] + o;
    }
    __syncthreads();
    #pragma unroll
    for (int r = 0; r < ROWS; ++r) {
        float s1 = xl[r], s2 = xl[r] * xl[r];
        #pragma unroll
        for (int m = 1; m < 64; m <<= 1) { s1 += __shfl_xor(s1, m); s2 += __shfl_xor(s2, m); }
        if (lane == 0) { red[wid][r][0] = s1; red[wid][r][1] = s2; }
    }
    __syncthreads();
    const float g2l = g2[l], b2l = b2[l];
    #pragma unroll
    for (int r = 0; r < ROWS; ++r) {
        float s1 = red[0][r][0] + red[1][r][0];
        float s2 = red[0][r][1] + red[1][r][1];
        float mu = s1 * (1.0f / HID);
        float var = s2 * (1.0f / HID) - mu * mu;
        float rstd = rsqrtf(var + 1e-5f);
        buf[r][l] = (xl[r] - mu) * rstd * g2l + b2l;
    }
    __syncthreads();
    float f0[ROWS], f1[ROWS];
    #pragma unroll
    for (int r = 0; r < ROWS; ++r) { f0[r] = 0.f; f1[r] = 0.f; }
    for (int k = 0; k < HID; ++k) {
        float w0 = Wf1[k * 256 + l], w1 = Wf1[k * 256 + l + 128];
        #pragma unroll
        for (int r = 0; r < ROWS; ++r) {
            float xv = buf[r][k];
            f0[r] = fmaf(xv, w0, f0[r]);
            f1[r] = fmaf(xv, w1, f1[r]);
        }
    }
    const float bf1a = bf1[l], bf1b = bf1[l + 128];
    #pragma unroll
    for (int r = 0; r < ROWS; ++r) {
        hbuf[r][l] = gelu_f(f0[r] + bf1a);
        hbuf[r][l + 128] = gelu_f(f1[r] + bf1b);
    }
    __syncthreads();
    float o2[ROWS];
    #pragma unroll
    for (int r = 0; r < ROWS; ++r) o2[r] = 0.f;
    for (int k = 0; k < 2 * HID; ++k) {
        float w = Wf2[k * HID + l];
        #pragma unroll
        for (int r = 0; r < ROWS; ++r) o2[r] = fmaf(hbuf[r][k], w, o2[r]);
    }
    const float bf2l = bf2[l];
    #pragma unroll
    for (int r = 0; r < ROWS; ++r)
        out[(size_t)(base + r) * HID + l] = xl[r] + o2[r] + bf2l;
}

extern "C" void kernel_launch(void* const* d_in, const int* in_sizes, int n_in,
                              void* d_out, int out_size, void* d_ws, size_t ws_size,
                              hipStream_t stream) {
    const float* x     = (const float*)d_in[0];
    const int*   ei    = (const int*)d_in[1];
    const float* ea    = (const float*)d_in[2];
    const float* gamma = (const float*)d_in[3];
    const float* beta  = (const float*)d_in[4];
    const float* ln1_g = (const float*)d_in[5];
    const float* ln1_b = (const float*)d_in[6];
    const float* Wq    = (const float*)d_in[7];
    const float* Wk    = (const float*)d_in[8];
    const float* Wv    = (const float*)d_in[9];
    const float* Wo    = (const float*)d_in[10];
    const float* bo    = (const float*)d_in[11];
    const float* Wea1  = (const float*)d_in[12];
    const float* bea1  = (const float*)d_in[13];
    const float* Wea2  = (const float*)d_in[14];
    const float* bea2  = (const float*)d_in[15];
    const float* Weg1  = (const float*)d_in[16];
    const float* beg1  = (const float*)d_in[17];
    const float* Weg2  = (const float*)d_in[18];
    const float* beg2  = (const float*)d_in[19];
    const float* ln2_g = (const float*)d_in[20];
    const float* ln2_b = (const float*)d_in[21];
    const float* Wf1   = (const float*)d_in[22];
    const float* bf1   = (const float*)d_in[23];
    const float* Wf2   = (const float*)d_in[24];
    const float* bf2   = (const float*)d_in[25];

    float* ws = (float*)d_ws;
    float* Q      = ws;
    float* K      = Q + (size_t)N_NODES * HID;
    float* V      = K + (size_t)N_NODES * HID;
    float* logits = V + (size_t)N_NODES * HID;     // E*4 floats, p-order; becomes el in-place
    float* mbuf   = logits + (size_t)E_EDGES * 4;
    float* sbuf   = mbuf + (size_t)N_NODES * 4;
    int*   deg    = (int*)(sbuf + (size_t)N_NODES * 4);
    float* agg    = (float*)(deg + N_NODES);
    int*   rowptr = (int*)(agg + (size_t)N_NODES * HID);
    int*   wptr   = rowptr + (N_NODES + 1);
    int*   bsum   = wptr + N_NODES;
    int*   eidx   = bsum + 128;
    int*   esrc   = eidx + E_EDGES;
    int*   pdst   = esrc + E_EDGES;

    // zero mbuf, sbuf, deg (agg no longer needs zeroing: k4 writes every element)
    hipMemsetAsync(mbuf, 0,
                   ((size_t)N_NODES * 4 * 2 + (size_t)N_NODES) * sizeof(float),
                   stream);

    // CSR build
    k0a_degree<<<E_EDGES / 256, 256, 0, stream>>>(ei, deg);
    k0b_scan1<<<SCAN_NB, SCAN_BS, 0, stream>>>(deg, rowptr, bsum);
    k0c_scan2<<<1, 128, 0, stream>>>(bsum);
    k0d_fixup<<<SCAN_NB, SCAN_BS, 0, stream>>>(rowptr, wptr, bsum);
    k0e_scatter<<<E_EDGES / 256, 256, 0, stream>>>(ei, wptr, eidx, esrc, pdst);

    k1_ln_qkv<<<N_NODES / ROWS, 128, 0, stream>>>(x, ln1_g, ln1_b, Wq, Wk, Wv, Q, K, V);
    k2_fused<<<(size_t)E_EDGES * 32 / 256, 256, 0, stream>>>(eidx, esrc, pdst, Q, K, ea,
                                                             Wea1, bea1, Wea2, bea2,
                                                             logits, mbuf);
    k3_exp_sum<<<E_EDGES / 256, 256, 0, stream>>>(pdst, mbuf, logits, sbuf);
    k4_mfma<<<N_NODES / (4 * NPW), 256, 0, stream>>>(rowptr, eidx, esrc, ea,
                                                     Weg1, beg1, Weg2, beg2,
                                                     logits, sbuf, V, agg);
    k5_out<<<N_NODES / ROWS, 128, 0, stream>>>(agg, Wo, bo, gamma, beta, x,
                                               ln2_g, ln2_b, Wf1, bf1, Wf2, bf2,
                                               (float*)d_out);
}

// Round 6
// 778.721 us; speedup vs baseline: 1.5880x; 1.0349x over previous
//
#include <hip/hip_runtime.h>
#include <cmath>

#define N_NODES 50000
#define E_EDGES 800000
#define HID 128
#define HEADS 4
#define HD 32
#define EDIM 16
#define EGD 32
#define ROWS 8
#define SCAN_BS 512
#define SCAN_NB ((N_NODES + SCAN_BS - 1) / SCAN_BS)

typedef __attribute__((ext_vector_type(8))) short bf16x8;
typedef __attribute__((ext_vector_type(4))) float f32x4;

__device__ __forceinline__ float gelu_f(float z) {
    return 0.5f * z * (1.0f + erff(z * 0.7071067811865476f));
}
__device__ __forceinline__ float sigmoid_fast(float z) {
    return __builtin_amdgcn_rcpf(1.0f + __expf(-z));
}
__device__ __forceinline__ short f2bf(float f) {
    unsigned u = __float_as_uint(f);
    unsigned r = u + 0x7fffu + ((u >> 16) & 1u);
    return (short)(r >> 16);
}
__device__ __forceinline__ float bf2f(unsigned short u) {
    return __uint_as_float(((unsigned)u) << 16);
}
__device__ __forceinline__ ushort4 f4bf(float4 v) {
    ushort4 r;
    r.x = (unsigned short)f2bf(v.x); r.y = (unsigned short)f2bf(v.y);
    r.z = (unsigned short)f2bf(v.z); r.w = (unsigned short)f2bf(v.w);
    return r;
}

// ---------------- K1: LN1 + QKV projection -> bf16 Q/K/V ----------------
__global__ void __launch_bounds__(128) k1_ln_qkv(
    const float* __restrict__ x, const float* __restrict__ g1, const float* __restrict__ b1,
    const float* __restrict__ Wq, const float* __restrict__ Wk, const float* __restrict__ Wv,
    unsigned short* __restrict__ Qb, unsigned short* __restrict__ Kb,
    unsigned short* __restrict__ Vb)
{
    __shared__ float xn[ROWS][HID];
    __shared__ float red[2][ROWS][2];
    const int l = threadIdx.x;
    const int wid = l >> 6, lane = l & 63;
    const int base = blockIdx.x * ROWS;
    float xv[ROWS];
    #pragma unroll
    for (int r = 0; r < ROWS; ++r) xv[r] = x[(size_t)(base + r) * HID + l];
    #pragma unroll
    for (int r = 0; r < ROWS; ++r) {
        float s1 = xv[r], s2 = xv[r] * xv[r];
        #pragma unroll
        for (int m = 1; m < 64; m <<= 1) { s1 += __shfl_xor(s1, m); s2 += __shfl_xor(s2, m); }
        if (lane == 0) { red[wid][r][0] = s1; red[wid][r][1] = s2; }
    }
    __syncthreads();
    const float gl = g1[l], bl = b1[l];
    #pragma unroll
    for (int r = 0; r < ROWS; ++r) {
        float s1 = red[0][r][0] + red[1][r][0];
        float s2 = red[0][r][1] + red[1][r][1];
        float mu = s1 * (1.0f / HID);
        float var = s2 * (1.0f / HID) - mu * mu;
        float rstd = rsqrtf(var + 1e-5f);
        xn[r][l] = (xv[r] - mu) * rstd * gl + bl;
    }
    __syncthreads();
    float aq[ROWS], ak[ROWS], av[ROWS];
    #pragma unroll
    for (int r = 0; r < ROWS; ++r) { aq[r] = 0.f; ak[r] = 0.f; av[r] = 0.f; }
    for (int k = 0; k < HID; ++k) {
        float wq = Wq[k * HID + l], wk = Wk[k * HID + l], wv = Wv[k * HID + l];
        #pragma unroll
        for (int r = 0; r < ROWS; ++r) {
            float xr = xn[r][k];
            aq[r] = fmaf(xr, wq, aq[r]);
            ak[r] = fmaf(xr, wk, ak[r]);
            av[r] = fmaf(xr, wv, av[r]);
        }
    }
    #pragma unroll
    for (int r = 0; r < ROWS; ++r) {
        Qb[(size_t)(base + r) * HID + l] = (unsigned short)f2bf(aq[r]);
        Kb[(size_t)(base + r) * HID + l] = (unsigned short)f2bf(ak[r]);
        Vb[(size_t)(base + r) * HID + l] = (unsigned short)f2bf(av[r]);
    }
}

// ---------------- CSR build ----------------
__global__ void __launch_bounds__(256) k0a_degree(
    const int* __restrict__ ei, int* __restrict__ deg)
{
    const int e = blockIdx.x * 256 + threadIdx.x;
    atomicAdd(deg + ei[E_EDGES + e], 1);
}

__global__ void __launch_bounds__(SCAN_BS) k0b_scan1(
    const int* __restrict__ deg, int* __restrict__ rowptr, int* __restrict__ bsum)
{
    __shared__ int sm[SCAN_BS];
    const int t = threadIdx.x;
    const int i = blockIdx.x * SCAN_BS + t;
    const int v = (i < N_NODES) ? deg[i] : 0;
    sm[t] = v;
    __syncthreads();
    #pragma unroll
    for (int off = 1; off < SCAN_BS; off <<= 1) {
        int add = (t >= off) ? sm[t - off] : 0;
        __syncthreads();
        sm[t] += add;
        __syncthreads();
    }
    if (i < N_NODES) rowptr[i] = sm[t] - v;
    if (t == SCAN_BS - 1) bsum[blockIdx.x] = sm[t];
}

__global__ void __launch_bounds__(128) k0c_scan2(int* __restrict__ bsum)
{
    __shared__ int sm[128];
    const int t = threadIdx.x;
    const int v = (t < SCAN_NB) ? bsum[t] : 0;
    sm[t] = v;
    __syncthreads();
    #pragma unroll
    for (int off = 1; off < 128; off <<= 1) {
        int add = (t >= off) ? sm[t - off] : 0;
        __syncthreads();
        sm[t] += add;
        __syncthreads();
    }
    if (t < SCAN_NB) bsum[t] = sm[t] - v; // exclusive
}

__global__ void __launch_bounds__(SCAN_BS) k0d_fixup(
    int* __restrict__ rowptr, int* __restrict__ wptr, const int* __restrict__ bsum)
{
    const int i = blockIdx.x * SCAN_BS + threadIdx.x;
    if (i < N_NODES) {
        int r = rowptr[i] + bsum[blockIdx.x];
        rowptr[i] = r;
        wptr[i] = r;
    }
    if (i == 0) rowptr[N_NODES] = E_EDGES;
}

__global__ void __launch_bounds__(256) k0e_scatter(
    const int* __restrict__ ei, int* __restrict__ wptr,
    int* __restrict__ eidx, int* __restrict__ esrc, int* __restrict__ pdst)
{
    const int e = blockIdx.x * 256 + threadIdx.x;
    const int d = ei[E_EDGES + e];
    const int pos = atomicAdd(wptr + d, 1);
    eidx[pos] = e;
    esrc[pos] = ei[e];
    pdst[pos] = d;
}

// ---------------- K2: bf16 QK^T dot + edge-bias MLP + atomicMax + eab emit ----------------
__global__ void __launch_bounds__(256) k2_fused(
    const int* __restrict__ eidx, const int* __restrict__ esrc, const int* __restrict__ pdst,
    const unsigned short* __restrict__ Qb, const unsigned short* __restrict__ Kb,
    const float* __restrict__ ea,
    const float* __restrict__ Wea1, const float* __restrict__ bea1,
    const float* __restrict__ Wea2, const float* __restrict__ bea2,
    float* __restrict__ logits, float* __restrict__ mbuf,
    unsigned short* __restrict__ eab)
{
    const int t = threadIdx.x;
    const int p = (blockIdx.x * 256 + t) >> 5;
    const int s = t & 31;
    const int e = eidx[p];
    const int src = esrc[p];
    const int dst = pdst[p];
    // QK dot in bf16: lane s covers elems 4s..4s+3; head = s>>3
    const ushort4 qu = ((const ushort4*)(Qb + (size_t)dst * HID))[s];
    const ushort4 ku = ((const ushort4*)(Kb + (size_t)src * HID))[s];
    float pr = bf2f(qu.x) * bf2f(ku.x) + bf2f(qu.y) * bf2f(ku.y)
             + bf2f(qu.z) * bf2f(ku.z) + bf2f(qu.w) * bf2f(ku.w);
    pr += __shfl_xor(pr, 1);
    pr += __shfl_xor(pr, 2);
    pr += __shfl_xor(pr, 4);
    const float4* eap = (const float4*)(ea + (size_t)e * EDIM);
    float4 a0 = eap[0], a1 = eap[1], a2 = eap[2], a3 = eap[3];
    // emit bf16 edge-attrs in p-order for k4 (streaming consumer)
    if (s < 4) {
        const float4 av = (s == 0) ? a0 : (s == 1) ? a1 : (s == 2) ? a2 : a3;
        ((ushort4*)(eab + (size_t)p * EDIM))[s] = f4bf(av);
    }
    float h = bea1[s];
    h = fmaf(a0.x, Wea1[0 * EGD + s], h);  h = fmaf(a0.y, Wea1[1 * EGD + s], h);
    h = fmaf(a0.z, Wea1[2 * EGD + s], h);  h = fmaf(a0.w, Wea1[3 * EGD + s], h);
    h = fmaf(a1.x, Wea1[4 * EGD + s], h);  h = fmaf(a1.y, Wea1[5 * EGD + s], h);
    h = fmaf(a1.z, Wea1[6 * EGD + s], h);  h = fmaf(a1.w, Wea1[7 * EGD + s], h);
    h = fmaf(a2.x, Wea1[8 * EGD + s], h);  h = fmaf(a2.y, Wea1[9 * EGD + s], h);
    h = fmaf(a2.z, Wea1[10 * EGD + s], h); h = fmaf(a2.w, Wea1[11 * EGD + s], h);
    h = fmaf(a3.x, Wea1[12 * EGD + s], h); h = fmaf(a3.y, Wea1[13 * EGD + s], h);
    h = fmaf(a3.z, Wea1[14 * EGD + s], h); h = fmaf(a3.w, Wea1[15 * EGD + s], h);
    h = gelu_f(h);
    const float4 w2 = ((const float4*)Wea2)[s];
    float b0 = h * w2.x, b1 = h * w2.y, b2 = h * w2.z, b3 = h * w2.w;
    #pragma unroll
    for (int off = 1; off < 32; off <<= 1) {
        b0 += __shfl_xor(b0, off);
        b1 += __shfl_xor(b1, off);
        b2 += __shfl_xor(b2, off);
        b3 += __shfl_xor(b3, off);
    }
    const float dv = __shfl(pr, (t & 32) + ((s & 3) << 3));
    if (s < 4) {
        const float bias = (s == 0) ? b0 : (s == 1) ? b1 : (s == 2) ? b2 : b3;
        const float lg = dv * 0.17677669529663689f + bias + bea2[s];
        logits[(size_t)p * 4 + s] = lg;
        if (lg > 0.f) atomicMax((int*)mbuf + (size_t)dst * 4 + s, __float_as_int(lg));
    }
}

// ---------------- K3: el = exp(logit - m); segmented-scan + one atomic per run ----------------
__global__ void __launch_bounds__(256) k3_exp_sum(
    const int* __restrict__ pdst, const float* __restrict__ mbuf,
    float* __restrict__ logits /* in: logits, out: el (p-order) */, float* __restrict__ sbuf)
{
    const int p = blockIdx.x * 256 + threadIdx.x;
    const int lane = threadIdx.x & 63;
    const int d = pdst[p];
    float4 lg = *(const float4*)(logits + (size_t)p * 4);
    const float4 mv = *(const float4*)(mbuf + (size_t)d * 4);
    lg.x = __expf(lg.x - mv.x);
    lg.y = __expf(lg.y - mv.y);
    lg.z = __expf(lg.z - mv.z);
    lg.w = __expf(lg.w - mv.w);
    *(float4*)(logits + (size_t)p * 4) = lg;
    float4 v = lg;
    #pragma unroll
    for (int off = 1; off < 64; off <<= 1) {
        const int du = __shfl_up(d, off);
        const float ux = __shfl_up(v.x, off);
        const float uy = __shfl_up(v.y, off);
        const float uz = __shfl_up(v.z, off);
        const float uw = __shfl_up(v.w, off);
        if (lane >= off && du == d) { v.x += ux; v.y += uy; v.z += uz; v.w += uw; }
    }
    const int dn = __shfl_down(d, 1);
    if (lane == 63 || dn != d) {
        atomicAdd(sbuf + (size_t)d * 4 + 0, v.x);
        atomicAdd(sbuf + (size_t)d * 4 + 1, v.y);
        atomicAdd(sbuf + (size_t)d * 4 + 2, v.z);
        atomicAdd(sbuf + (size_t)d * 4 + 3, v.w);
    }
}

// ---------------- K4: MFMA gate MLP + attn-V fold; 1 wave = 1 node, no atomics ----------------
// A: row=lane&15, k=(lane>>4)*8+j.  B: col=lane&15, k=(lane>>4)*8+j (consistent-k).
// C/D (verified): col=lane&15, row=(lane>>4)*4+reg.
__global__ void __launch_bounds__(256) k4_mfma(
    const int* __restrict__ rowptr, const int* __restrict__ esrc,
    const unsigned short* __restrict__ eab,
    const float* __restrict__ Weg1, const float* __restrict__ beg1,
    const float* __restrict__ Weg2, const float* __restrict__ beg2,
    const float* __restrict__ el, const float* __restrict__ sbuf,
    const unsigned short* __restrict__ Vb, float* __restrict__ agg)
{
    __shared__ short h_lds[4][16 * EGD];      // per-wave [edge][hidden] bf16
    __shared__ float attn_lds[4][16][4];      // per-wave [edge][head]
    const int t = threadIdx.x;
    const int wid = t >> 6, l = t & 63;
    const int q = l >> 4, c15 = l & 15;

    // B2 fragments: Weg2[k = q*8+j][col = tt*16 + c15]
    bf16x8 b2[8];
    #pragma unroll
    for (int tt = 0; tt < 8; ++tt) {
        #pragma unroll
        for (int j = 0; j < 8; ++j)
            b2[tt][j] = f2bf(Weg2[(q * 8 + j) * HID + tt * 16 + c15]);
    }
    // B1 fragments (K padded 16->32: quarters 2,3 are zero)
    bf16x8 b1f[2];
    #pragma unroll
    for (int n = 0; n < 2; ++n) {
        #pragma unroll
        for (int j = 0; j < 8; ++j)
            b1f[n][j] = (q < 2) ? f2bf(Weg1[(q * 8 + j) * EGD + n * 16 + c15]) : (short)0;
    }
    const float b1c0 = beg1[c15], b1c1 = beg1[16 + c15];
    float bg2[8];
    #pragma unroll
    for (int tt = 0; tt < 8; ++tt) bg2[tt] = beg2[tt * 16 + c15];

    const f32x4 zc = {0.f, 0.f, 0.f, 0.f};
    const int n = blockIdx.x * 4 + wid;   // one node per wave
    const int pstart = rowptr[n], pend = rowptr[n + 1];
    const float invh = __builtin_amdgcn_rcpf(sbuf[(size_t)n * 4 + (l & 3)] + 1e-10f);
    float accv[8];
    #pragma unroll
    for (int tt = 0; tt < 8; ++tt) accv[tt] = 0.f;

    for (int pc = pstart; pc < pend; pc += 16) {
        const int cnt = min(16, pend - pc);
        // ---- stage: lanes q<2 load A1 (eab, streaming bf16), lanes q>=2 stage attn ----
        bf16x8 a1 = {0, 0, 0, 0, 0, 0, 0, 0};
        if (q < 2) {
            if (c15 < cnt)
                a1 = *(const bf16x8*)(eab + (size_t)(pc + c15) * EDIM + q * 8);
        } else {
            const int idx2 = l & 31;
            const int slot = idx2 >> 2, head = idx2 & 3;
            float v0 = 0.f, v1 = 0.f;
            if (slot < cnt)     v0 = el[(size_t)(pc + slot) * 4 + head] * invh;
            if (slot + 8 < cnt) v1 = el[(size_t)(pc + slot + 8) * 4 + head] * invh;
            attn_lds[wid][slot][head] = v0;
            attn_lds[wid][slot + 8][head] = v1;
        }
        // ---- layer-1 MFMA: h_pre = ea @ Weg1 ----
        f32x4 c0 = __builtin_amdgcn_mfma_f32_16x16x32_bf16(a1, b1f[0], zc, 0, 0, 0);
        f32x4 c1 = __builtin_amdgcn_mfma_f32_16x16x32_bf16(a1, b1f[1], zc, 0, 0, 0);
        #pragma unroll
        for (int r = 0; r < 4; ++r) {
            h_lds[wid][(q * 4 + r) * EGD + c15]      = f2bf(gelu_f(c0[r] + b1c0));
            h_lds[wid][(q * 4 + r) * EGD + 16 + c15] = f2bf(gelu_f(c1[r] + b1c1));
        }
        asm volatile("s_waitcnt lgkmcnt(0)" ::: "memory");
        __builtin_amdgcn_sched_barrier(0);
        // ---- gather A2 / attn / src ----
        const bf16x8 a2 = *(const bf16x8*)&h_lds[wid][c15 * EGD + q * 8];
        f32x4 at[4];
        int srcr[4];
        #pragma unroll
        for (int r = 0; r < 4; ++r) {
            at[r] = *(const f32x4*)&attn_lds[wid][q * 4 + r][0];
            srcr[r] = (q * 4 + r < cnt) ? esrc[pc + q * 4 + r] : 0;
        }
        // ---- layer-2 MFMA: G = h @ Weg2 ----
        f32x4 g[8];
        #pragma unroll
        for (int tt = 0; tt < 8; ++tt)
            g[tt] = __builtin_amdgcn_mfma_f32_16x16x32_bf16(a2, b2[tt], zc, 0, 0, 0);
        // ---- fold: accv[tt] += attn * sigmoid(G + b) * V[src][col] ----
        #pragma unroll
        for (int tt = 0; tt < 8; ++tt) {
            #pragma unroll
            for (int r = 0; r < 4; ++r) {
                const float sg = sigmoid_fast(g[tt][r] + bg2[tt]);
                const float aw = (tt < 2) ? at[r][0] : (tt < 4) ? at[r][1]
                               : (tt < 6) ? at[r][2] : at[r][3];
                const float vv = bf2f(Vb[(size_t)srcr[r] * HID + tt * 16 + c15]);
                accv[tt] = fmaf(aw * sg, vv, accv[tt]);
            }
        }
    }
    // ---- cross-quarter reduce + direct store (no atomics) ----
    #pragma unroll
    for (int tt = 0; tt < 8; ++tt) {
        accv[tt] += __shfl_xor(accv[tt], 16);
        accv[tt] += __shfl_xor(accv[tt], 32);
    }
    agg[(size_t)n * HID + (2 * q) * 16 + c15]     = accv[2 * q];
    agg[(size_t)n * HID + (2 * q + 1) * 16 + c15] = accv[2 * q + 1];
}

// ---------------- K5: Wo + FiLM + residual + LN2 + FFN + residual ----------------
__global__ void __launch_bounds__(128) k5_out(
    const float* __restrict__ agg, const float* __restrict__ Wo, const float* __restrict__ bo,
    const float* __restrict__ gamma, const float* __restrict__ beta,
    const float* __restrict__ x,
    const float* __restrict__ g2, const float* __restrict__ b2,
    const float* __restrict__ Wf1, const float* __restrict__ bf1,
    const float* __restrict__ Wf2, const float* __restrict__ bf2,
    float* __restrict__ out)
{
    __shared__ float buf[ROWS][HID];
    __shared__ float hbuf[ROWS][2 * HID];
    __shared__ float red[2][ROWS][2];
    const int l = threadIdx.x;
    const int wid = l >> 6, lane = l & 63;
    const int base = blockIdx.x * ROWS;
    #pragma unroll
    for (int r = 0; r < ROWS; ++r) buf[r][l] = agg[(size_t)(base + r) * HID + l];
    __syncthreads();
    float acc[ROWS];
    #pragma unroll
    for (int r = 0; r < ROWS; ++r) acc[r] = 0.f;
    for (int k = 0; k < HID; ++k) {
        float w = Wo[k * HID + l];
        #pragma unroll
        for (int r = 0; r < ROWS; ++r) acc[r] = fmaf(buf[r][k], w, acc[r]);
    }
    float xl[ROWS];
    const float bol = bo[l];
    #pragma unroll
    for (int r = 0; r < ROWS; ++r) {
        float o = acc[r] + bol;
        size_t idx = (size_t)(base + r) * HID + l;
        o = fmaf(gamma[idx], o, beta[idx]);
        xl[r] = x[idx] + o;
    }
    __syncthreads();
    #pragma unroll
    for (int r = 0; r < ROWS; ++r) {
        float s1 = xl[r], s2 = xl[r] * xl[r];
        #pragma unroll
        for (int m = 1; m < 64; m <<= 1) { s1 += __shfl_xor(s1, m); s2 += __shfl_xor(s2, m); }
        if (lane == 0) { red[wid][r][0] = s1; red[wid][r][1] = s2; }
    }
    __syncthreads();
    const float g2l = g2[l], b2l = b2[l];
    #pragma unroll
    for (int r = 0; r < ROWS; ++r) {
        float s1 = red[0][r][0] + red[1][r][0];
        float s2 = red[0][r][1] + red[1][r][1];
        float mu = s1 * (1.0f / HID);
        float var = s2 * (1.0f / HID) - mu * mu;
        float rstd = rsqrtf(var + 1e-5f);
        buf[r][l] = (xl[r] - mu) * rstd * g2l + b2l;
    }
    __syncthreads();
    float f0[ROWS], f1[ROWS];
    #pragma unroll
    for (int r = 0; r < ROWS; ++r) { f0[r] = 0.f; f1[r] = 0.f; }
    for (int k = 0; k < HID; ++k) {
        float w0 = Wf1[k * 256 + l], w1 = Wf1[k * 256 + l + 128];
        #pragma unroll
        for (int r = 0; r < ROWS; ++r) {
            float xv = buf[r][k];
            f0[r] = fmaf(xv, w0, f0[r]);
            f1[r] = fmaf(xv, w1, f1[r]);
        }
    }
    const float bf1a = bf1[l], bf1b = bf1[l + 128];
    #pragma unroll
    for (int r = 0; r < ROWS; ++r) {
        hbuf[r][l] = gelu_f(f0[r] + bf1a);
        hbuf[r][l + 128] = gelu_f(f1[r] + bf1b);
    }
    __syncthreads();
    float o2[ROWS];
    #pragma unroll
    for (int r = 0; r < ROWS; ++r) o2[r] = 0.f;
    for (int k = 0; k < 2 * HID; ++k) {
        float w = Wf2[k * HID + l];
        #pragma unroll
        for (int r = 0; r < ROWS; ++r) o2[r] = fmaf(hbuf[r][k], w, o2[r]);
    }
    const float bf2l = bf2[l];
    #pragma unroll
    for (int r = 0; r < ROWS; ++r)
        out[(size_t)(base + r) * HID + l] = xl[r] + o2[r] + bf2l;
}

extern "C" void kernel_launch(void* const* d_in, const int* in_sizes, int n_in,
                              void* d_out, int out_size, void* d_ws, size_t ws_size,
                              hipStream_t stream) {
    const float* x     = (const float*)d_in[0];
    const int*   ei    = (const int*)d_in[1];
    const float* ea    = (const float*)d_in[2];
    const float* gamma = (const float*)d_in[3];
    const float* beta  = (const float*)d_in[4];
    const float* ln1_g = (const float*)d_in[5];
    const float* ln1_b = (const float*)d_in[6];
    const float* Wq    = (const float*)d_in[7];
    const float* Wk    = (const float*)d_in[8];
    const float* Wv    = (const float*)d_in[9];
    const float* Wo    = (const float*)d_in[10];
    const float* bo    = (const float*)d_in[11];
    const float* Wea1  = (const float*)d_in[12];
    const float* bea1  = (const float*)d_in[13];
    const float* Wea2  = (const float*)d_in[14];
    const float* bea2  = (const float*)d_in[15];
    const float* Weg1  = (const float*)d_in[16];
    const float* beg1  = (const float*)d_in[17];
    const float* Weg2  = (const float*)d_in[18];
    const float* beg2  = (const float*)d_in[19];
    const float* ln2_g = (const float*)d_in[20];
    const float* ln2_b = (const float*)d_in[21];
    const float* Wf1   = (const float*)d_in[22];
    const float* bf1   = (const float*)d_in[23];
    const float* Wf2   = (const float*)d_in[24];
    const float* bf2   = (const float*)d_in[25];

    // workspace layout (16B-aligned vector-load regions)
    unsigned short* Qb  = (unsigned short*)d_ws;
    unsigned short* Kb  = Qb + (size_t)N_NODES * HID;
    unsigned short* Vb  = Kb + (size_t)N_NODES * HID;
    unsigned short* eab = Vb + (size_t)N_NODES * HID;          // E*16 bf16, p-order
    float* logits = (float*)(eab + (size_t)E_EDGES * EDIM);    // E*4, p-order; becomes el
    float* mbuf   = logits + (size_t)E_EDGES * 4;
    float* sbuf   = mbuf + (size_t)N_NODES * 4;
    int*   deg    = (int*)(sbuf + (size_t)N_NODES * 4);
    float* agg    = (float*)(deg + N_NODES);
    int*   rowptr = (int*)(agg + (size_t)N_NODES * HID);
    int*   wptr   = rowptr + (N_NODES + 1);
    int*   bsum   = wptr + N_NODES;
    int*   eidx   = bsum + 128;
    int*   esrc   = eidx + E_EDGES;
    int*   pdst   = esrc + E_EDGES;

    // zero mbuf, sbuf, deg (contiguous); agg fully written by k4
    hipMemsetAsync(mbuf, 0,
                   ((size_t)N_NODES * 4 * 2) * sizeof(float) + (size_t)N_NODES * sizeof(int),
                   stream);

    // CSR build
    k0a_degree<<<E_EDGES / 256, 256, 0, stream>>>(ei, deg);
    k0b_scan1<<<SCAN_NB, SCAN_BS, 0, stream>>>(deg, rowptr, bsum);
    k0c_scan2<<<1, 128, 0, stream>>>(bsum);
    k0d_fixup<<<SCAN_NB, SCAN_BS, 0, stream>>>(rowptr, wptr, bsum);
    k0e_scatter<<<E_EDGES / 256, 256, 0, stream>>>(ei, wptr, eidx, esrc, pdst);

    k1_ln_qkv<<<N_NODES / ROWS, 128, 0, stream>>>(x, ln1_g, ln1_b, Wq, Wk, Wv, Qb, Kb, Vb);
    k2_fused<<<(size_t)E_EDGES * 32 / 256, 256, 0, stream>>>(eidx, esrc, pdst, Qb, Kb, ea,
                                                             Wea1, bea1, Wea2, bea2,
                                                             logits, mbuf, eab);
    k3_exp_sum<<<E_EDGES / 256, 256, 0, stream>>>(pdst, mbuf, logits, sbuf);
    k4_mfma<<<N_NODES / 4, 256, 0, stream>>>(rowptr, esrc, eab,
                                             Weg1, beg1, Weg2, beg2,
                                             logits, sbuf, Vb, agg);
    k5_out<<<N_NODES / ROWS, 128, 0, stream>>>(agg, Wo, bo, gamma, beta, x,
                                               ln2_g, ln2_b, Wf1, bf1, Wf2, bf2,
                                               (float*)d_out);
}

// Round 7
// 737.918 us; speedup vs baseline: 1.6758x; 1.0553x over previous
//
#include <hip/hip_runtime.h>
#include <cmath>

#define N_NODES 50000
#define E_EDGES 800000
#define HID 128
#define HEADS 4
#define HD 32
#define EDIM 16
#define EGD 32
#define ROWS 8
#define VSTRIDE 136   // ushorts per staged V row (272B = 256B + 16B pad)
#define SCAN_BS 512
#define SCAN_NB ((N_NODES + SCAN_BS - 1) / SCAN_BS)

typedef __attribute__((ext_vector_type(8))) short bf16x8;
typedef __attribute__((ext_vector_type(4))) float f32x4;

__device__ __forceinline__ float gelu_f(float z) {
    return 0.5f * z * (1.0f + erff(z * 0.7071067811865476f));
}
__device__ __forceinline__ float sigmoid_fast(float z) {
    return __builtin_amdgcn_rcpf(1.0f + __expf(-z));
}
__device__ __forceinline__ short f2bf(float f) {
    unsigned u = __float_as_uint(f);
    unsigned r = u + 0x7fffu + ((u >> 16) & 1u);
    return (short)(r >> 16);
}
__device__ __forceinline__ float bf2f(unsigned short u) {
    return __uint_as_float(((unsigned)u) << 16);
}
__device__ __forceinline__ ushort4 f4bf(float4 v) {
    ushort4 r;
    r.x = (unsigned short)f2bf(v.x); r.y = (unsigned short)f2bf(v.y);
    r.z = (unsigned short)f2bf(v.z); r.w = (unsigned short)f2bf(v.w);
    return r;
}

// ---------------- K1: LN1 + QKV projection -> bf16 Q/K/V ----------------
__global__ void __launch_bounds__(128) k1_ln_qkv(
    const float* __restrict__ x, const float* __restrict__ g1, const float* __restrict__ b1,
    const float* __restrict__ Wq, const float* __restrict__ Wk, const float* __restrict__ Wv,
    unsigned short* __restrict__ Qb, unsigned short* __restrict__ Kb,
    unsigned short* __restrict__ Vb)
{
    __shared__ float xn[ROWS][HID];
    __shared__ float red[2][ROWS][2];
    const int l = threadIdx.x;
    const int wid = l >> 6, lane = l & 63;
    const int base = blockIdx.x * ROWS;
    float xv[ROWS];
    #pragma unroll
    for (int r = 0; r < ROWS; ++r) xv[r] = x[(size_t)(base + r) * HID + l];
    #pragma unroll
    for (int r = 0; r < ROWS; ++r) {
        float s1 = xv[r], s2 = xv[r] * xv[r];
        #pragma unroll
        for (int m = 1; m < 64; m <<= 1) { s1 += __shfl_xor(s1, m); s2 += __shfl_xor(s2, m); }
        if (lane == 0) { red[wid][r][0] = s1; red[wid][r][1] = s2; }
    }
    __syncthreads();
    const float gl = g1[l], bl = b1[l];
    #pragma unroll
    for (int r = 0; r < ROWS; ++r) {
        float s1 = red[0][r][0] + red[1][r][0];
        float s2 = red[0][r][1] + red[1][r][1];
        float mu = s1 * (1.0f / HID);
        float var = s2 * (1.0f / HID) - mu * mu;
        float rstd = rsqrtf(var + 1e-5f);
        xn[r][l] = (xv[r] - mu) * rstd * gl + bl;
    }
    __syncthreads();
    float aq[ROWS], ak[ROWS], av[ROWS];
    #pragma unroll
    for (int r = 0; r < ROWS; ++r) { aq[r] = 0.f; ak[r] = 0.f; av[r] = 0.f; }
    for (int k = 0; k < HID; ++k) {
        float wq = Wq[k * HID + l], wk = Wk[k * HID + l], wv = Wv[k * HID + l];
        #pragma unroll
        for (int r = 0; r < ROWS; ++r) {
            float xr = xn[r][k];
            aq[r] = fmaf(xr, wq, aq[r]);
            ak[r] = fmaf(xr, wk, ak[r]);
            av[r] = fmaf(xr, wv, av[r]);
        }
    }
    #pragma unroll
    for (int r = 0; r < ROWS; ++r) {
        Qb[(size_t)(base + r) * HID + l] = (unsigned short)f2bf(aq[r]);
        Kb[(size_t)(base + r) * HID + l] = (unsigned short)f2bf(ak[r]);
        Vb[(size_t)(base + r) * HID + l] = (unsigned short)f2bf(av[r]);
    }
}

// ---------------- CSR build ----------------
__global__ void __launch_bounds__(256) k0a_degree(
    const int* __restrict__ ei, int* __restrict__ deg)
{
    const int e = blockIdx.x * 256 + threadIdx.x;
    atomicAdd(deg + ei[E_EDGES + e], 1);
}

__global__ void __launch_bounds__(SCAN_BS) k0b_scan1(
    const int* __restrict__ deg, int* __restrict__ rowptr, int* __restrict__ bsum)
{
    __shared__ int sm[SCAN_BS];
    const int t = threadIdx.x;
    const int i = blockIdx.x * SCAN_BS + t;
    const int v = (i < N_NODES) ? deg[i] : 0;
    sm[t] = v;
    __syncthreads();
    #pragma unroll
    for (int off = 1; off < SCAN_BS; off <<= 1) {
        int add = (t >= off) ? sm[t - off] : 0;
        __syncthreads();
        sm[t] += add;
        __syncthreads();
    }
    if (i < N_NODES) rowptr[i] = sm[t] - v;
    if (t == SCAN_BS - 1) bsum[blockIdx.x] = sm[t];
}

__global__ void __launch_bounds__(128) k0c_scan2(int* __restrict__ bsum)
{
    __shared__ int sm[128];
    const int t = threadIdx.x;
    const int v = (t < SCAN_NB) ? bsum[t] : 0;
    sm[t] = v;
    __syncthreads();
    #pragma unroll
    for (int off = 1; off < 128; off <<= 1) {
        int add = (t >= off) ? sm[t - off] : 0;
        __syncthreads();
        sm[t] += add;
        __syncthreads();
    }
    if (t < SCAN_NB) bsum[t] = sm[t] - v; // exclusive
}

__global__ void __launch_bounds__(SCAN_BS) k0d_fixup(
    int* __restrict__ rowptr, int* __restrict__ wptr, const int* __restrict__ bsum)
{
    const int i = blockIdx.x * SCAN_BS + threadIdx.x;
    if (i < N_NODES) {
        int r = rowptr[i] + bsum[blockIdx.x];
        rowptr[i] = r;
        wptr[i] = r;
    }
    if (i == 0) rowptr[N_NODES] = E_EDGES;
}

__global__ void __launch_bounds__(256) k0e_scatter(
    const int* __restrict__ ei, int* __restrict__ wptr,
    int* __restrict__ eidx, int* __restrict__ esrc, int* __restrict__ pdst)
{
    const int e = blockIdx.x * 256 + threadIdx.x;
    const int d = ei[E_EDGES + e];
    const int pos = atomicAdd(wptr + d, 1);
    eidx[pos] = e;
    esrc[pos] = ei[e];
    pdst[pos] = d;
}

// ---------------- K2: bf16 QK^T dot + edge-bias MLP + atomicMax + eab emit ----------------
__global__ void __launch_bounds__(256) k2_fused(
    const int* __restrict__ eidx, const int* __restrict__ esrc, const int* __restrict__ pdst,
    const unsigned short* __restrict__ Qb, const unsigned short* __restrict__ Kb,
    const float* __restrict__ ea,
    const float* __restrict__ Wea1, const float* __restrict__ bea1,
    const float* __restrict__ Wea2, const float* __restrict__ bea2,
    float* __restrict__ logits, float* __restrict__ mbuf,
    unsigned short* __restrict__ eab)
{
    const int t = threadIdx.x;
    const int p = (blockIdx.x * 256 + t) >> 5;
    const int s = t & 31;
    const int e = eidx[p];
    const int src = esrc[p];
    const int dst = pdst[p];
    // QK dot in bf16: lane s covers elems 4s..4s+3; head = s>>3
    const ushort4 qu = ((const ushort4*)(Qb + (size_t)dst * HID))[s];
    const ushort4 ku = ((const ushort4*)(Kb + (size_t)src * HID))[s];
    float pr = bf2f(qu.x) * bf2f(ku.x) + bf2f(qu.y) * bf2f(ku.y)
             + bf2f(qu.z) * bf2f(ku.z) + bf2f(qu.w) * bf2f(ku.w);
    pr += __shfl_xor(pr, 1);
    pr += __shfl_xor(pr, 2);
    pr += __shfl_xor(pr, 4);
    const float4* eap = (const float4*)(ea + (size_t)e * EDIM);
    float4 a0 = eap[0], a1 = eap[1], a2 = eap[2], a3 = eap[3];
    // emit bf16 edge-attrs in p-order for k4 (streaming consumer)
    if (s < 4) {
        const float4 av = (s == 0) ? a0 : (s == 1) ? a1 : (s == 2) ? a2 : a3;
        ((ushort4*)(eab + (size_t)p * EDIM))[s] = f4bf(av);
    }
    float h = bea1[s];
    h = fmaf(a0.x, Wea1[0 * EGD + s], h);  h = fmaf(a0.y, Wea1[1 * EGD + s], h);
    h = fmaf(a0.z, Wea1[2 * EGD + s], h);  h = fmaf(a0.w, Wea1[3 * EGD + s], h);
    h = fmaf(a1.x, Wea1[4 * EGD + s], h);  h = fmaf(a1.y, Wea1[5 * EGD + s], h);
    h = fmaf(a1.z, Wea1[6 * EGD + s], h);  h = fmaf(a1.w, Wea1[7 * EGD + s], h);
    h = fmaf(a2.x, Wea1[8 * EGD + s], h);  h = fmaf(a2.y, Wea1[9 * EGD + s], h);
    h = fmaf(a2.z, Wea1[10 * EGD + s], h); h = fmaf(a2.w, Wea1[11 * EGD + s], h);
    h = fmaf(a3.x, Wea1[12 * EGD + s], h); h = fmaf(a3.y, Wea1[13 * EGD + s], h);
    h = fmaf(a3.z, Wea1[14 * EGD + s], h); h = fmaf(a3.w, Wea1[15 * EGD + s], h);
    h = gelu_f(h);
    const float4 w2 = ((const float4*)Wea2)[s];
    float b0 = h * w2.x, b1 = h * w2.y, b2 = h * w2.z, b3 = h * w2.w;
    #pragma unroll
    for (int off = 1; off < 32; off <<= 1) {
        b0 += __shfl_xor(b0, off);
        b1 += __shfl_xor(b1, off);
        b2 += __shfl_xor(b2, off);
        b3 += __shfl_xor(b3, off);
    }
    const float dv = __shfl(pr, (t & 32) + ((s & 3) << 3));
    if (s < 4) {
        const float bias = (s == 0) ? b0 : (s == 1) ? b1 : (s == 2) ? b2 : b3;
        const float lg = dv * 0.17677669529663689f + bias + bea2[s];
        logits[(size_t)p * 4 + s] = lg;
        if (lg > 0.f) atomicMax((int*)mbuf + (size_t)dst * 4 + s, __float_as_int(lg));
    }
}

// ---------------- K3: el = exp(logit - m); segmented-scan + one atomic per run ----------------
__global__ void __launch_bounds__(256) k3_exp_sum(
    const int* __restrict__ pdst, const float* __restrict__ mbuf,
    float* __restrict__ logits /* in: logits, out: el (p-order) */, float* __restrict__ sbuf)
{
    const int p = blockIdx.x * 256 + threadIdx.x;
    const int lane = threadIdx.x & 63;
    const int d = pdst[p];
    float4 lg = *(const float4*)(logits + (size_t)p * 4);
    const float4 mv = *(const float4*)(mbuf + (size_t)d * 4);
    lg.x = __expf(lg.x - mv.x);
    lg.y = __expf(lg.y - mv.y);
    lg.z = __expf(lg.z - mv.z);
    lg.w = __expf(lg.w - mv.w);
    *(float4*)(logits + (size_t)p * 4) = lg;
    float4 v = lg;
    #pragma unroll
    for (int off = 1; off < 64; off <<= 1) {
        const int du = __shfl_up(d, off);
        const float ux = __shfl_up(v.x, off);
        const float uy = __shfl_up(v.y, off);
        const float uz = __shfl_up(v.z, off);
        const float uw = __shfl_up(v.w, off);
        if (lane >= off && du == d) { v.x += ux; v.y += uy; v.z += uz; v.w += uw; }
    }
    const int dn = __shfl_down(d, 1);
    if (lane == 63 || dn != d) {
        atomicAdd(sbuf + (size_t)d * 4 + 0, v.x);
        atomicAdd(sbuf + (size_t)d * 4 + 1, v.y);
        atomicAdd(sbuf + (size_t)d * 4 + 2, v.z);
        atomicAdd(sbuf + (size_t)d * 4 + 3, v.w);
    }
}

// ---------------- K4: MFMA gate MLP + attn-V fold; 1 wave = 1 node, V staged via LDS ----------------
// A: row=lane&15, k=(lane>>4)*8+j.  B: col=lane&15, k=(lane>>4)*8+j (consistent-k).
// C/D (verified): col=lane&15, row=(lane>>4)*4+reg.
__global__ void __launch_bounds__(256) k4_mfma(
    const int* __restrict__ rowptr, const int* __restrict__ esrc,
    const unsigned short* __restrict__ eab,
    const float* __restrict__ Weg1, const float* __restrict__ beg1,
    const float* __restrict__ Weg2, const float* __restrict__ beg2,
    const float* __restrict__ el, const float* __restrict__ sbuf,
    const unsigned short* __restrict__ Vb, float* __restrict__ agg)
{
    __shared__ __align__(16) short h_lds[4][16 * EGD];        // per-wave [edge][hidden] bf16
    __shared__ __align__(16) float attn_lds[4][16][4];        // per-wave [edge][head]
    __shared__ __align__(16) unsigned short vsm[4][16 * VSTRIDE]; // per-wave staged V rows
    const int t = threadIdx.x;
    const int wid = t >> 6, l = t & 63;
    const int q = l >> 4, c15 = l & 15;

    // B2 fragments: Weg2[k = q*8+j][col = tt*16 + c15]
    bf16x8 b2[8];
    #pragma unroll
    for (int tt = 0; tt < 8; ++tt) {
        #pragma unroll
        for (int j = 0; j < 8; ++j)
            b2[tt][j] = f2bf(Weg2[(q * 8 + j) * HID + tt * 16 + c15]);
    }
    // B1 fragments (K padded 16->32: quarters 2,3 are zero)
    bf16x8 b1f[2];
    #pragma unroll
    for (int n = 0; n < 2; ++n) {
        #pragma unroll
        for (int j = 0; j < 8; ++j)
            b1f[n][j] = (q < 2) ? f2bf(Weg1[(q * 8 + j) * EGD + n * 16 + c15]) : (short)0;
    }
    const float b1c0 = beg1[c15], b1c1 = beg1[16 + c15];
    float bg2[8];
    #pragma unroll
    for (int tt = 0; tt < 8; ++tt) bg2[tt] = beg2[tt * 16 + c15];

    const f32x4 zc = {0.f, 0.f, 0.f, 0.f};
    const int n = blockIdx.x * 4 + wid;   // one node per wave
    const int pstart = rowptr[n], pend = rowptr[n + 1];
    const float invh = __builtin_amdgcn_rcpf(sbuf[(size_t)n * 4 + (l & 3)] + 1e-10f);
    float accv[8];
    #pragma unroll
    for (int tt = 0; tt < 8; ++tt) accv[tt] = 0.f;

    const int srow = l >> 2;   // staging: this lane covers V row slot srow
    const int ssub = l & 3;    // quarter of the 256B row (64B each)

    for (int pc = pstart; pc < pend; pc += 16) {
        const int cnt = min(16, pend - pc);
        // ---- 1) issue V-row staging loads FIRST (latency hides under MFMA1/gelu) ----
        const int sidx = (srow < cnt) ? srow : cnt - 1;
        const int srcrow = esrc[pc + sidx];
        bf16x8 vreg[4];
        #pragma unroll
        for (int i = 0; i < 4; ++i)
            vreg[i] = *(const bf16x8*)(Vb + (size_t)srcrow * HID + ssub * 32 + i * 8);
        // ---- 2) stage: lanes q<2 load A1 (eab, streaming bf16), lanes q>=2 stage attn ----
        bf16x8 a1 = {0, 0, 0, 0, 0, 0, 0, 0};
        if (q < 2) {
            if (c15 < cnt)
                a1 = *(const bf16x8*)(eab + (size_t)(pc + c15) * EDIM + q * 8);
        } else {
            const int idx2 = l & 31;
            const int slot = idx2 >> 2, head = idx2 & 3;
            float v0 = 0.f, v1 = 0.f;
            if (slot < cnt)     v0 = el[(size_t)(pc + slot) * 4 + head] * invh;
            if (slot + 8 < cnt) v1 = el[(size_t)(pc + slot + 8) * 4 + head] * invh;
            attn_lds[wid][slot][head] = v0;
            attn_lds[wid][slot + 8][head] = v1;
        }
        // ---- 3) layer-1 MFMA: h_pre = ea @ Weg1 ----
        f32x4 c0 = __builtin_amdgcn_mfma_f32_16x16x32_bf16(a1, b1f[0], zc, 0, 0, 0);
        f32x4 c1 = __builtin_amdgcn_mfma_f32_16x16x32_bf16(a1, b1f[1], zc, 0, 0, 0);
        #pragma unroll
        for (int r = 0; r < 4; ++r) {
            h_lds[wid][(q * 4 + r) * EGD + c15]      = f2bf(gelu_f(c0[r] + b1c0));
            h_lds[wid][(q * 4 + r) * EGD + 16 + c15] = f2bf(gelu_f(c1[r] + b1c1));
        }
        // ---- 4) write staged V rows into LDS (vmcnt wait happens here) ----
        #pragma unroll
        for (int i = 0; i < 4; ++i)
            *(bf16x8*)&vsm[wid][srow * VSTRIDE + ssub * 32 + i * 8] = vreg[i];
        asm volatile("s_waitcnt lgkmcnt(0)" ::: "memory");
        __builtin_amdgcn_sched_barrier(0);
        // ---- 5) gather A2 / attn ----
        const bf16x8 a2 = *(const bf16x8*)&h_lds[wid][c15 * EGD + q * 8];
        f32x4 at[4];
        #pragma unroll
        for (int r = 0; r < 4; ++r)
            at[r] = *(const f32x4*)&attn_lds[wid][q * 4 + r][0];
        // ---- 6) layer-2 MFMA: G = h @ Weg2 ----
        f32x4 g[8];
        #pragma unroll
        for (int tt = 0; tt < 8; ++tt)
            g[tt] = __builtin_amdgcn_mfma_f32_16x16x32_bf16(a2, b2[tt], zc, 0, 0, 0);
        // ---- 7) fold: accv[tt] += attn * sigmoid(G + b) * Vlds[row][col] ----
        #pragma unroll
        for (int tt = 0; tt < 8; ++tt) {
            #pragma unroll
            for (int r = 0; r < 4; ++r) {
                const float sg = sigmoid_fast(g[tt][r] + bg2[tt]);
                const float aw = (tt < 2) ? at[r][0] : (tt < 4) ? at[r][1]
                               : (tt < 6) ? at[r][2] : at[r][3];
                const float vv = bf2f(vsm[wid][(q * 4 + r) * VSTRIDE + tt * 16 + c15]);
                accv[tt] = fmaf(aw * sg, vv, accv[tt]);
            }
        }
    }
    // ---- cross-quarter reduce + direct store (no atomics) ----
    #pragma unroll
    for (int tt = 0; tt < 8; ++tt) {
        accv[tt] += __shfl_xor(accv[tt], 16);
        accv[tt] += __shfl_xor(accv[tt], 32);
    }
    agg[(size_t)n * HID + (2 * q) * 16 + c15]     = accv[2 * q];
    agg[(size_t)n * HID + (2 * q + 1) * 16 + c15] = accv[2 * q + 1];
}

// ---------------- K5: Wo + FiLM + residual + LN2 + FFN + residual ----------------
__global__ void __launch_bounds__(128) k5_out(
    const float* __restrict__ agg, const float* __restrict__ Wo, const float* __restrict__ bo,
    const float* __restrict__ gamma, const float* __restrict__ beta,
    const float* __restrict__ x,
    const float* __restrict__ g2, const float* __restrict__ b2,
    const float* __restrict__ Wf1, const float* __restrict__ bf1,
    const float* __restrict__ Wf2, const float* __restrict__ bf2,
    float* __restrict__ out)
{
    __shared__ float buf[ROWS][HID];
    __shared__ float hbuf[ROWS][2 * HID];
    __shared__ float red[2][ROWS][2];
    const int l = threadIdx.x;
    const int wid = l >> 6, lane = l & 63;
    const int base = blockIdx.x * ROWS;
    #pragma unroll
    for (int r = 0; r < ROWS; ++r) buf[r][l] = agg[(size_t)(base + r) * HID + l];
    __syncthreads();
    float acc[ROWS];
    #pragma unroll
    for (int r = 0; r < ROWS; ++r) acc[r] = 0.f;
    for (int k = 0; k < HID; ++k) {
        float w = Wo[k * HID + l];
        #pragma unroll
        for (int r = 0; r < ROWS; ++r) acc[r] = fmaf(buf[r][k], w, acc[r]);
    }
    float xl[ROWS];
    const float bol = bo[l];
    #pragma unroll
    for (int r = 0; r < ROWS; ++r) {
        float o = acc[r] + bol;
        size_t idx = (size_t)(base + r) * HID + l;
        o = fmaf(gamma[idx], o, beta[idx]);
        xl[r] = x[idx] + o;
    }
    __syncthreads();
    #pragma unroll
    for (int r = 0; r < ROWS; ++r) {
        float s1 = xl[r], s2 = xl[r] * xl[r];
        #pragma unroll
        for (int m = 1; m < 64; m <<= 1) { s1 += __shfl_xor(s1, m); s2 += __shfl_xor(s2, m); }
        if (lane == 0) { red[wid][r][0] = s1; red[wid][r][1] = s2; }
    }
    __syncthreads();
    const float g2l = g2[l], b2l = b2[l];
    #pragma unroll
    for (int r = 0; r < ROWS; ++r) {
        float s1 = red[0][r][0] + red[1][r][0];
        float s2 = red[0][r][1] + red[1][r][1];
        float mu = s1 * (1.0f / HID);
        float var = s2 * (1.0f / HID) - mu * mu;
        float rstd = rsqrtf(var + 1e-5f);
        buf[r][l] = (xl[r] - mu) * rstd * g2l + b2l;
    }
    __syncthreads();
    float f0[ROWS], f1[ROWS];
    #pragma unroll
    for (int r = 0; r < ROWS; ++r) { f0[r] = 0.f; f1[r] = 0.f; }
    for (int k = 0; k < HID; ++k) {
        float w0 = Wf1[k * 256 + l], w1 = Wf1[k * 256 + l + 128];
        #pragma unroll
        for (int r = 0; r < ROWS; ++r) {
            float xv = buf[r][k];
            f0[r] = fmaf(xv, w0, f0[r]);
            f1[r] = fmaf(xv, w1, f1[r]);
        }
    }
    const float bf1a = bf1[l], bf1b = bf1[l + 128];
    #pragma unroll
    for (int r = 0; r < ROWS; ++r) {
        hbuf[r][l] = gelu_f(f0[r] + bf1a);
        hbuf[r][l + 128] = gelu_f(f1[r] + bf1b);
    }
    __syncthreads();
    float o2[ROWS];
    #pragma unroll
    for (int r = 0; r < ROWS; ++r) o2[r] = 0.f;
    for (int k = 0; k < 2 * HID; ++k) {
        float w = Wf2[k * HID + l];
        #pragma unroll
        for (int r = 0; r < ROWS; ++r) o2[r] = fmaf(hbuf[r][k], w, o2[r]);
    }
    const float bf2l = bf2[l];
    #pragma unroll
    for (int r = 0; r < ROWS; ++r)
        out[(size_t)(base + r) * HID + l] = xl[r] + o2[r] + bf2l;
}

extern "C" void kernel_launch(void* const* d_in, const int* in_sizes, int n_in,
                              void* d_out, int out_size, void* d_ws, size_t ws_size,
                              hipStream_t stream) {
    const float* x     = (const float*)d_in[0];
    const int*   ei    = (const int*)d_in[1];
    const float* ea    = (const float*)d_in[2];
    const float* gamma = (const float*)d_in[3];
    const float* beta  = (const float*)d_in[4];
    const float* ln1_g = (const float*)d_in[5];
    const float* ln1_b = (const float*)d_in[6];
    const float* Wq    = (const float*)d_in[7];
    const float* Wk    = (const float*)d_in[8];
    const float* Wv    = (const float*)d_in[9];
    const float* Wo    = (const float*)d_in[10];
    const float* bo    = (const float*)d_in[11];
    const float* Wea1  = (const float*)d_in[12];
    const float* bea1  = (const float*)d_in[13];
    const float* Wea2  = (const float*)d_in[14];
    const float* bea2  = (const float*)d_in[15];
    const float* Weg1  = (const float*)d_in[16];
    const float* beg1  = (const float*)d_in[17];
    const float* Weg2  = (const float*)d_in[18];
    const float* beg2  = (const float*)d_in[19];
    const float* ln2_g = (const float*)d_in[20];
    const float* ln2_b = (const float*)d_in[21];
    const float* Wf1   = (const float*)d_in[22];
    const float* bf1   = (const float*)d_in[23];
    const float* Wf2   = (const float*)d_in[24];
    const float* bf2   = (const float*)d_in[25];

    // workspace layout (16B-aligned vector-load regions)
    unsigned short* Qb  = (unsigned short*)d_ws;
    unsigned short* Kb  = Qb + (size_t)N_NODES * HID;
    unsigned short* Vb  = Kb + (size_t)N_NODES * HID;
    unsigned short* eab = Vb + (size_t)N_NODES * HID;          // E*16 bf16, p-order
    float* logits = (float*)(eab + (size_t)E_EDGES * EDIM);    // E*4, p-order; becomes el
    float* mbuf   = logits + (size_t)E_EDGES * 4;
    float* sbuf   = mbuf + (size_t)N_NODES * 4;
    int*   deg    = (int*)(sbuf + (size_t)N_NODES * 4);
    float* agg    = (float*)(deg + N_NODES);
    int*   rowptr = (int*)(agg + (size_t)N_NODES * HID);
    int*   wptr   = rowptr + (N_NODES + 1);
    int*   bsum   = wptr + N_NODES;
    int*   eidx   = bsum + 128;
    int*   esrc   = eidx + E_EDGES;
    int*   pdst   = esrc + E_EDGES;

    // zero mbuf, sbuf, deg (contiguous); agg fully written by k4
    hipMemsetAsync(mbuf, 0,
                   ((size_t)N_NODES * 4 * 2) * sizeof(float) + (size_t)N_NODES * sizeof(int),
                   stream);

    // CSR build
    k0a_degree<<<E_EDGES / 256, 256, 0, stream>>>(ei, deg);
    k0b_scan1<<<SCAN_NB, SCAN_BS, 0, stream>>>(deg, rowptr, bsum);
    k0c_scan2<<<1, 128, 0, stream>>>(bsum);
    k0d_fixup<<<SCAN_NB, SCAN_BS, 0, stream>>>(rowptr, wptr, bsum);
    k0e_scatter<<<E_EDGES / 256, 256, 0, stream>>>(ei, wptr, eidx, esrc, pdst);

    k1_ln_qkv<<<N_NODES / ROWS, 128, 0, stream>>>(x, ln1_g, ln1_b, Wq, Wk, Wv, Qb, Kb, Vb);
    k2_fused<<<(size_t)E_EDGES * 32 / 256, 256, 0, stream>>>(eidx, esrc, pdst, Qb, Kb, ea,
                                                             Wea1, bea1, Wea2, bea2,
                                                             logits, mbuf, eab);
    k3_exp_sum<<<E_EDGES / 256, 256, 0, stream>>>(pdst, mbuf, logits, sbuf);
    k4_mfma<<<N_NODES / 4, 256, 0, stream>>>(rowptr, esrc, eab,
                                             Weg1, beg1, Weg2, beg2,
                                             logits, sbuf, Vb, agg);
    k5_out<<<N_NODES / ROWS, 128, 0, stream>>>(agg, Wo, bo, gamma, beta, x,
                                               ln2_g, ln2_b, Wf1, bf1, Wf2, bf2,
                                               (float*)d_out);
}